// Round 6
// baseline (26958.707 us; speedup 1.0000x reference)
//
#include <hip/hip_runtime.h>
#include <hip/hip_cooperative_groups.h>
#include <math.h>

namespace cg = cooperative_groups;

#define B_    64
#define APER_ 16
#define A_    1024
#define TPAST_ 20
#define TFUT_  30
#define C_    256
#define M_    128
#define N_    256
#define H_    5
#define EMB_  16
#define D_    384
#define TTOT_ 50

#define WP_LD 400
#define RP_LD 656
#define LDSD_FLOATS 6320   // kq 16*132 + S 16*260 + 3*16

typedef short bf16x8 __attribute__((ext_vector_type(8)));
typedef float f32x4 __attribute__((ext_vector_type(4)));

__device__ __forceinline__ float sigmoidf_(float x) { return 1.0f / (1.0f + expf(-x)); }
__device__ __forceinline__ float softplusf_(float x) { return (x > 20.0f) ? x : log1pf(expf(x)); }
__device__ __forceinline__ unsigned short f2bf(float f) {
    unsigned u = __float_as_uint(f);
    return (unsigned short)((u + 0x7FFFu + ((u >> 16) & 1u)) >> 16);
}
__device__ __forceinline__ float bf2f(short s) {
    return __uint_as_float(((unsigned)(unsigned short)s) << 16);
}

// ---------------------------------------------------------------------------
// Prologue kernels (regular launches)
// ---------------------------------------------------------------------------
__global__ __launch_bounds__(256) void convert_w(const float* __restrict__ src, short* __restrict__ dst,
                                                 int srcRows, int srcK, int dstK, int total)
{
    const int idx = blockIdx.x * 256 + threadIdx.x;
    if (idx >= total) return;
    const int r = idx / dstK, k = idx % dstK;
    float v = (k < srcK && r < srcRows) ? src[(size_t)r * srcK + k] : 0.f;
    dst[idx] = (short)f2bf(v);
}

__global__ __launch_bounds__(256) void embed_k(const float* __restrict__ x,
                                               const float* __restrict__ w1, const float* __restrict__ b1,
                                               const float* __restrict__ w2, const float* __restrict__ b2,
                                               short* __restrict__ emb)
{
    const int idx = blockIdx.x * 256 + threadIdx.x;
    if (idx >= A_ * TPAST_) return;
    const int a = idx / TPAST_, t = idx % TPAST_;
    const float x0 = x[(size_t)idx * 2], x1 = x[(size_t)idx * 2 + 1];
    float hbuf[8];
    #pragma unroll
    for (int j = 0; j < 8; ++j) hbuf[j] = fmaxf(0.f, w1[j * 2] * x0 + w1[j * 2 + 1] * x1 + b1[j]);
    short* e = emb + ((size_t)t * A_ + a) * EMB_;
    #pragma unroll
    for (int i = 0; i < 16; ++i) {
        float acc = b2[i];
        #pragma unroll
        for (int j = 0; j < 8; ++j) acc += w2[i * 8 + j] * hbuf[j];
        e[i] = (short)f2bf(acc);
    }
}

__global__ __launch_bounds__(256) void init_k(float* __restrict__ h, const float* __restrict__ h_bias, short* __restrict__ hb,
                                              float* __restrict__ hr, const float* __restrict__ hr_bias, short* __restrict__ hrb,
                                              float* __restrict__ hf, const float* __restrict__ hf_bias, short* __restrict__ hfb,
                                              short* __restrict__ reads_b, const float* __restrict__ init_r,
                                              float* __restrict__ mem,
                                              float* __restrict__ normsG, const float* __restrict__ mem_bias)
{
    const int idx = blockIdx.x * 256 + threadIdx.x;
    if (idx < B_ * N_ * M_) mem[idx] = mem_bias[idx & (N_ * M_ - 1)];
    if (idx < B_ * N_) {
        const float* r = mem_bias + (size_t)(idx & (N_ - 1)) * M_;
        float ss = 0.f;
        for (int k = 0; k < M_; ++k) ss += r[k] * r[k];
        normsG[idx] = sqrtf(ss) + 1e-16f;
    }
    if (idx < A_ * C_) {
        float v = h_bias[idx & (C_ - 1)];
        h[idx] = v; hb[idx] = (short)f2bf(v);
        v = hr_bias[idx & (C_ - 1)];
        hr[idx] = v; hrb[idx] = (short)f2bf(v);
    }
    if (idx < H_ * A_ * D_) {
        float v = hf_bias[idx % D_];
        hf[idx] = v; hfb[idx] = (short)f2bf(v);
    }
    if (idx < A_ * M_) reads_b[idx] = (short)f2bf(init_r[idx & (M_ - 1)]);
}

// ---------------------------------------------------------------------------
// Device tile functions (same math as round-5 kernels)
// ---------------------------------------------------------------------------
__device__ __forceinline__ void gru_tile(
    const short* __restrict__ X1, int K1,
    const short* __restrict__ X2, int K2,
    const short* __restrict__ Wih, int Kpad,
    const float* __restrict__ bih,
    const short* __restrict__ Hb, const short* __restrict__ Whh,
    const float* __restrict__ bhh,
    const float* __restrict__ Hprev,
    float* __restrict__ Hnew, short* __restrict__ Hnewb,
    int G, int rowBase, int colBase, int lane)
{
    const int l16 = lane & 15;
    const int kb8 = (lane >> 4) * 8;

    f32x4 gi[3][2][2], gh[3][2][2];
    const f32x4 z4 = {0.f, 0.f, 0.f, 0.f};
    #pragma unroll
    for (int g = 0; g < 3; ++g)
        #pragma unroll
        for (int i = 0; i < 2; ++i)
            #pragma unroll
            for (int j = 0; j < 2; ++j) { gi[g][i][j] = z4; gh[g][i][j] = z4; }

    for (int kc = 0; kc < Kpad; kc += 32) {
        bf16x8 afr[2];
        const int k8 = kc + kb8;
        #pragma unroll
        for (int i = 0; i < 2; ++i) {
            const int r = rowBase + i * 16 + l16;
            bf16x8 v = {0, 0, 0, 0, 0, 0, 0, 0};
            if (k8 < K1) {
                if (X1) v = *(const bf16x8*)(X1 + (size_t)(r & 1023) * K1 + k8);
            } else if (k8 < K1 + K2) {
                v = *(const bf16x8*)(X2 + (size_t)r * K2 + (k8 - K1));
            }
            afr[i] = v;
        }
        #pragma unroll
        for (int g = 0; g < 3; ++g)
            #pragma unroll
            for (int j = 0; j < 2; ++j) {
                const bf16x8 b = *(const bf16x8*)(Wih + (size_t)(g * G + colBase + j * 16 + l16) * Kpad + k8);
                gi[g][0][j] = __builtin_amdgcn_mfma_f32_16x16x32_bf16(afr[0], b, gi[g][0][j], 0, 0, 0);
                gi[g][1][j] = __builtin_amdgcn_mfma_f32_16x16x32_bf16(afr[1], b, gi[g][1][j], 0, 0, 0);
            }
    }
    for (int kc = 0; kc < G; kc += 32) {
        const int k8 = kc + kb8;
        bf16x8 afr[2];
        #pragma unroll
        for (int i = 0; i < 2; ++i)
            afr[i] = *(const bf16x8*)(Hb + (size_t)(rowBase + i * 16 + l16) * G + k8);
        #pragma unroll
        for (int g = 0; g < 3; ++g)
            #pragma unroll
            for (int j = 0; j < 2; ++j) {
                const bf16x8 b = *(const bf16x8*)(Whh + (size_t)(g * G + colBase + j * 16 + l16) * G + k8);
                gh[g][0][j] = __builtin_amdgcn_mfma_f32_16x16x32_bf16(afr[0], b, gh[g][0][j], 0, 0, 0);
                gh[g][1][j] = __builtin_amdgcn_mfma_f32_16x16x32_bf16(afr[1], b, gh[g][1][j], 0, 0, 0);
            }
    }

    const int r4 = (lane >> 4) * 4;
    #pragma unroll
    for (int j = 0; j < 2; ++j) {
        const int col = colBase + j * 16 + l16;
        const float bi0 = bih[col],         bh0 = bhh[col];
        const float bi1 = bih[G + col],     bh1 = bhh[G + col];
        const float bi2 = bih[2 * G + col], bh2 = bhh[2 * G + col];
        #pragma unroll
        for (int i = 0; i < 2; ++i) {
            #pragma unroll
            for (int q = 0; q < 4; ++q) {
                const int row = rowBase + i * 16 + r4 + q;
                const float rr = sigmoidf_(gi[0][i][j][q] + bi0 + gh[0][i][j][q] + bh0);
                const float zz = sigmoidf_(gi[1][i][j][q] + bi1 + gh[1][i][j][q] + bh1);
                const float nn = tanhf(gi[2][i][j][q] + bi2 + rr * (gh[2][i][j][q] + bh2));
                const float hp = Hprev[(size_t)row * G + col];
                const float hv = (1.f - zz) * nn + zz * hp;
                Hnew[(size_t)row * G + col] = hv;
                Hnewb[(size_t)row * G + col] = (short)f2bf(hv);
            }
        }
    }
}

__device__ __forceinline__ void gemm_tile(
    const short* __restrict__ Xb, const short* __restrict__ Wb,
    const float* __restrict__ bias, float* __restrict__ Out,
    int Ncols, int ldOut, int K, int rowBase, int colBase, int lane)
{
    const int l16 = lane & 15;
    const int kb8 = (lane >> 4) * 8;
    const f32x4 z4 = {0.f, 0.f, 0.f, 0.f};
    f32x4 acc[2][2] = {{z4, z4}, {z4, z4}};

    for (int kc = 0; kc < K; kc += 32) {
        const int k8 = kc + kb8;
        const bf16x8 a0 = *(const bf16x8*)(Xb + (size_t)(rowBase + l16) * K + k8);
        const bf16x8 a1 = *(const bf16x8*)(Xb + (size_t)(rowBase + 16 + l16) * K + k8);
        const bf16x8 b0 = *(const bf16x8*)(Wb + (size_t)(colBase + l16) * K + k8);
        const bf16x8 b1 = *(const bf16x8*)(Wb + (size_t)(colBase + 16 + l16) * K + k8);
        acc[0][0] = __builtin_amdgcn_mfma_f32_16x16x32_bf16(a0, b0, acc[0][0], 0, 0, 0);
        acc[0][1] = __builtin_amdgcn_mfma_f32_16x16x32_bf16(a0, b1, acc[0][1], 0, 0, 0);
        acc[1][0] = __builtin_amdgcn_mfma_f32_16x16x32_bf16(a1, b0, acc[1][0], 0, 0, 0);
        acc[1][1] = __builtin_amdgcn_mfma_f32_16x16x32_bf16(a1, b1, acc[1][1], 0, 0, 0);
    }
    const int r4 = (lane >> 4) * 4;
    #pragma unroll
    for (int j = 0; j < 2; ++j) {
        const int col = colBase + j * 16 + l16;
        if (col >= Ncols) continue;
        const float bv = bias[col];
        #pragma unroll
        for (int i = 0; i < 2; ++i)
            #pragma unroll
            for (int q = 0; q < 4; ++q) {
                const int row = rowBase + i * 16 + r4 + q;
                Out[(size_t)row * ldOut + col] = acc[i][j][q] + bv;
            }
    }
}

// Wave-level NTM write: one wave per agent. lane = s*4+q: slot s, quarter q (32 dims).
__device__ __forceinline__ void write_agent(const float* __restrict__ wp, float* __restrict__ mem,
                                            float* __restrict__ normsG, int a, int lane)
{
    const int s = lane >> 2, q = lane & 3;
    const int b = a >> 4, pg = a & 15;
    const float* w = wp + (size_t)a * WP_LD;
    float* mrow = mem + ((size_t)(b * N_) + pg * 16 + s) * M_ + q * 32;
    float mv[32];
    #pragma unroll
    for (int i = 0; i < 32; i += 4) {
        const float4 m4 = *(const float4*)(mrow + i);
        mv[i] = m4.x; mv[i + 1] = m4.y; mv[i + 2] = m4.z; mv[i + 3] = m4.w;
    }
    float dot = 0.f, ss = 0.f, kss = 0.f;
    #pragma unroll
    for (int i = 0; i < 32; ++i) {
        const float kv = tanhf(w[q * 32 + i]);
        kss += kv * kv; dot += kv * mv[i]; ss += mv[i] * mv[i];
    }
    dot += __shfl_xor(dot, 1); dot += __shfl_xor(dot, 2);
    ss  += __shfl_xor(ss, 1);  ss  += __shfl_xor(ss, 2);
    kss += __shfl_xor(kss, 1); kss += __shfl_xor(kss, 2);
    const float beta = softplusf_(w[128]);
    const float logit = beta * (dot / ((sqrtf(ss) + 1e-16f) * (sqrtf(kss) + 1e-16f)));
    float mx = logit;
    #pragma unroll
    for (int d = 4; d < 64; d <<= 1) mx = fmaxf(mx, __shfl_xor(mx, d));
    const float e = __expf(logit - mx);
    float sum = e;
    #pragma unroll
    for (int d = 4; d < 64; d <<= 1) sum += __shfl_xor(sum, d);
    const float wwv = e / sum;
    float ssq = 0.f;
    float vout[32];
    #pragma unroll
    for (int i = 0; i < 32; ++i) {
        const float erv = sigmoidf_(w[129 + q * 32 + i]);
        const float adv = tanhf(w[257 + q * 32 + i]);
        const float v = mv[i] * (1.f - wwv * erv) + wwv * adv;
        vout[i] = v; ssq += v * v;
    }
    #pragma unroll
    for (int i = 0; i < 32; i += 4)
        *(float4*)(mrow + i) = make_float4(vout[i], vout[i + 1], vout[i + 2], vout[i + 3]);
    ssq += __shfl_xor(ssq, 1); ssq += __shfl_xor(ssq, 2);
    if (q == 0) normsG[b * N_ + pg * 16 + s] = sqrtf(ssq) + 1e-16f;
}

// Block-subgroup NTM read (256 threads per task). Barriers hit by ALL threads.
__device__ void read_task(const float* __restrict__ rp, const float* __restrict__ mem,
                          const float* __restrict__ normsG, short* __restrict__ reads_b,
                          float* lds, int task, bool active, int tl)
{
    float* kq = lds;                      // 16*132
    float* S = lds + 2112;               // 16*260
    float* beta_s = lds + 2112 + 4160;   // 16
    float* knorm_s = beta_s + 16;
    float* inv_s = knorm_s + 16;
    const int h = task >> 6, b = task & 63;
    const int a = tl >> 4, sub = tl & 15;

    if (active) {
        const float* base = rp + (size_t)(b * 16 + a) * RP_LD + h * 129;
        const int k0 = sub * 8;
        float v[8]; float ssk = 0.f;
        #pragma unroll
        for (int r = 0; r < 8; ++r) { v[r] = tanhf(base[k0 + r]); ssk += v[r] * v[r]; }
        float* dst = kq + a * 132 + k0;
        *(float4*)dst = make_float4(v[0], v[1], v[2], v[3]);
        *(float4*)(dst + 4) = make_float4(v[4], v[5], v[6], v[7]);
        #pragma unroll
        for (int m = 1; m < 16; m <<= 1) ssk += __shfl_xor(ssk, m);
        if (sub == 0) {
            knorm_s[a] = sqrtf(ssk) + 1e-16f;
            beta_s[a] = softplusf_(base[128]);
        }
    }
    __syncthreads();

    if (active) {
        const int wave = tl >> 6, lane = tl & 63;
        const int l16 = lane & 15, kb8 = (lane >> 4) * 8;
        const int slotBase = wave * 64;
        const f32x4 z4 = {0.f, 0.f, 0.f, 0.f};
        f32x4 acc[4] = {z4, z4, z4, z4};
        const float* mb = mem + (size_t)b * N_ * M_;
        #pragma unroll
        for (int kc = 0; kc < 128; kc += 32) {
            const float* ap = kq + l16 * 132 + kc + kb8;
            bf16x8 ah, al;
            #pragma unroll
            for (int r = 0; r < 8; ++r) {
                const float av = ap[r];
                const short hv = (short)f2bf(av);
                ah[r] = hv; al[r] = (short)f2bf(av - bf2f(hv));
            }
            #pragma unroll
            for (int tt = 0; tt < 4; ++tt) {
                const float* bp = mb + (size_t)(slotBase + tt * 16 + l16) * M_ + kc + kb8;
                bf16x8 bh, bl;
                #pragma unroll
                for (int r = 0; r < 8; ++r) {
                    const float bv = bp[r];
                    const short hv = (short)f2bf(bv);
                    bh[r] = hv; bl[r] = (short)f2bf(bv - bf2f(hv));
                }
                acc[tt] = __builtin_amdgcn_mfma_f32_16x16x32_bf16(ah, bh, acc[tt], 0, 0, 0);
                acc[tt] = __builtin_amdgcn_mfma_f32_16x16x32_bf16(ah, bl, acc[tt], 0, 0, 0);
                acc[tt] = __builtin_amdgcn_mfma_f32_16x16x32_bf16(al, bh, acc[tt], 0, 0, 0);
            }
        }
        const int r4 = (lane >> 4) * 4;
        #pragma unroll
        for (int tt = 0; tt < 4; ++tt) {
            const int slot = slotBase + tt * 16 + l16;
            const float nv = normsG[b * N_ + slot];
            #pragma unroll
            for (int q = 0; q < 4; ++q) {
                const int aq = r4 + q;
                const float lg = ((slot >> 4) == aq) ? -1e30f
                               : beta_s[aq] * acc[tt][q] / (nv * knorm_s[aq]);
                S[aq * 260 + slot] = lg;
            }
        }
    }
    __syncthreads();

    if (active) {
        float mx = -1e30f;
        #pragma unroll
        for (int i = 0; i < 16; ++i) mx = fmaxf(mx, S[a * 260 + sub + 16 * i]);
        #pragma unroll
        for (int m = 1; m < 16; m <<= 1) mx = fmaxf(mx, __shfl_xor(mx, m));
        float e[16]; float sum = 0.f;
        #pragma unroll
        for (int i = 0; i < 16; ++i) { e[i] = __expf(S[a * 260 + sub + 16 * i] - mx); sum += e[i]; }
        #pragma unroll
        for (int i = 0; i < 16; ++i) S[a * 260 + sub + 16 * i] = e[i];
        #pragma unroll
        for (int m = 1; m < 16; m <<= 1) sum += __shfl_xor(sum, m);
        if (sub == 0) inv_s[a] = 1.f / sum;
    }
    __syncthreads();

    if (active) {
        const int m0 = sub * 8;
        const float* mb = mem + (size_t)b * N_ * M_ + m0;
        float acc[8];
        #pragma unroll
        for (int r = 0; r < 8; ++r) acc[r] = 0.f;
        const float* Sa = S + a * 260;
        #pragma unroll 4
        for (int n = 0; n < N_; ++n) {
            const float w = Sa[n];
            const float4 v0 = *(const float4*)(mb + (size_t)n * M_);
            const float4 v1 = *(const float4*)(mb + (size_t)n * M_ + 4);
            acc[0] = fmaf(w, v0.x, acc[0]); acc[1] = fmaf(w, v0.y, acc[1]);
            acc[2] = fmaf(w, v0.z, acc[2]); acc[3] = fmaf(w, v0.w, acc[3]);
            acc[4] = fmaf(w, v1.x, acc[4]); acc[5] = fmaf(w, v1.y, acc[5]);
            acc[6] = fmaf(w, v1.z, acc[6]); acc[7] = fmaf(w, v1.w, acc[7]);
        }
        const float inv = inv_s[a];
        short pk[8];
        #pragma unroll
        for (int r = 0; r < 8; ++r) pk[r] = (short)f2bf(acc[r] * inv);
        *(bf16x8*)(reads_b + ((size_t)h * A_ + b * 16 + a) * M_ + m0) = *(bf16x8*)pk;
    }
}

__device__ __forceinline__ void out_row(const float* __restrict__ hf,
                                        const float* __restrict__ out_w, const float* __restrict__ out_b,
                                        float* __restrict__ predrel, int row, int t, int lane)
{
    const float* hrow = hf + (size_t)row * D_;
    float a0 = 0.f, a1 = 0.f;
    for (int k = lane; k < D_; k += 64) {
        const float v = hrow[k];
        a0 += v * out_w[k];
        a1 += v * out_w[D_ + k];
    }
    #pragma unroll
    for (int off = 32; off > 0; off >>= 1) { a0 += __shfl_down(a0, off); a1 += __shfl_down(a1, off); }
    if (lane == 0) {
        const int hh = row >> 10, a = row & 1023;
        float* o = predrel + (((size_t)a * H_ + hh) * TFUT_ + t) * 2;
        o[0] = a0 + out_b[0];
        o[1] = a1 + out_b[1];
    }
}

// ---------------------------------------------------------------------------
// The persistent cooperative kernel: full 50-step recurrence.
// Grid 256 blocks x 512 threads (2048 waves, 1 block/CU co-resident).
// ---------------------------------------------------------------------------
struct KParams {
    const short *enc_wih, *enc_whh, *rel_wih, *rel_whh, *dec_wih, *dec_whh, *write_w, *read_w;
    const float *enc_bih, *enc_bhh, *rel_bih, *rel_bhh, *dec_bih, *dec_bhh, *write_b, *read_b;
    const float *out_w, *out_b, *past;
    const short *emb_p, *emb_r;
    float *h0, *h1, *hr0, *hr1, *hf0, *hf1, *mem, *wp, *rp, *normsG;
    short *hb0, *hb1, *hrb0, *hrb1, *hfb0, *hfb1, *reads_b;
    float *pred, *predrel;
};

__global__ __launch_bounds__(512, 1) void model_loop(KParams p)
{
    cg::grid_group grid = cg::this_grid();
    __shared__ __align__(16) float ldsD[2 * LDSD_FLOATS];
    const int wb = threadIdx.x >> 6;
    const int lane = threadIdx.x & 63;
    const int gw = ((int)blockIdx.x << 3) | wb;     // 0..2047

    float *hc = p.h0, *hn = p.h1, *hrc = p.hr0, *hrn = p.hr1, *hfc = p.hf0, *hfn = p.hf1;
    short *hbc = p.hb0, *hbn = p.hb1, *hrbc = p.hrb0, *hrbn = p.hrb1, *hfbc = p.hfb0, *hfbn = p.hfb1;

    for (int t = 0; t < TTOT_; ++t) {
        // ---- phase A: enc GRU (256 tiles) | rel GRU (256 tiles) | out(t-1) on idle waves ----
        if (gw < 256) {
            const short* ep = (t < TPAST_) ? p.emb_p + (size_t)t * A_ * EMB_ : nullptr;
            gru_tile(ep, 16, p.reads_b, 128, p.enc_wih, 160, p.enc_bih,
                     hbc, p.enc_whh, p.enc_bhh, hc, hn, hbn, C_,
                     (gw >> 3) * 32, (gw & 7) * 32, lane);
        } else if (gw < 512) {
            const int tw = gw - 256;
            const short* er = (t < TPAST_) ? p.emb_r + (size_t)t * A_ * EMB_ : nullptr;
            gru_tile(er, 16, nullptr, 0, p.rel_wih, 32, p.rel_bih,
                     hrbc, p.rel_whh, p.rel_bhh, hrc, hrn, hrbn, C_,
                     (tw >> 3) * 32, (tw & 7) * 32, lane);
        } else if (t > TPAST_) {
            for (int r = gw - 512; r < H_ * A_; r += 1536)
                out_row(hfc, p.out_w, p.out_b, p.predrel, r, t - 1 - TPAST_, lane);
        }
        __threadfence(); grid.sync();

        // ---- phase B: write-head GEMM (416 tiles) | read-head GEMM (672 tiles) ----
        if (gw < 416) {
            gemm_tile(hbn, p.write_w, p.write_b, p.wp, 385, WP_LD, C_,
                      (gw & 31) * 32, (gw >> 5) * 32, lane);
        } else if (gw < 1088) {
            const int tw = gw - 416;
            gemm_tile(hrbn, p.read_w, p.read_b, p.rp, 645, RP_LD, C_,
                      (tw & 31) * 32, (tw >> 5) * 32, lane);
        }
        __threadfence(); grid.sync();

        // ---- phase C: memory write (1024 agents, one wave each) ----
        if (gw < A_) write_agent(p.wp, p.mem, p.normsG, gw, lane);
        __threadfence(); grid.sync();

        // ---- phase D: memory read (320 tasks, 256-thread subgroups) ----
        {
            const int group = threadIdx.x >> 8;
            const int task = (int)blockIdx.x + group * 256;
            read_task(p.rp, p.mem, p.normsG, p.reads_b,
                      ldsD + group * LDSD_FLOATS, task, task < B_ * H_, threadIdx.x & 255);
        }
        __threadfence(); grid.sync();

        // ---- phase E: decoder GRU (1920 tiles) ----
        if (gw < 1920) {
            gru_tile(hbn, 256, p.reads_b, 128, p.dec_wih, 384, p.dec_bih,
                     hfbc, p.dec_whh, p.dec_bhh, hfc, hfn, hfbn, D_,
                     (gw / 12) * 32, (gw % 12) * 32, lane);
        }
        __threadfence(); grid.sync();

        // swap state buffers (uniform across all threads)
        float* tf; short* ts;
        tf = hc; hc = hn; hn = tf;       ts = hbc; hbc = hbn; hbn = ts;
        tf = hrc; hrc = hrn; hrn = tf;   ts = hrbc; hrbc = hrbn; hrbn = ts;
        tf = hfc; hfc = hfn; hfn = tf;   ts = hfbc; hfbc = hfbn; hfbn = ts;
    }

    // final out projection (t = TTOT-1)
    for (int r = gw; r < H_ * A_; r += 2048)
        out_row(hfc, p.out_w, p.out_b, p.predrel, r, TTOT_ - 1 - TPAST_, lane);
    __threadfence(); grid.sync();

    // cumsum epilogue
    {
        const int idx = (int)blockIdx.x * 512 + threadIdx.x;
        if (idx < A_ * H_ * 2) {
            const int c = idx & 1;
            const int ah = idx >> 1;
            const int a = ah / H_;
            float acc = p.past[((size_t)a * TPAST_ + TPAST_ - 1) * 2 + c];
            const float* pr = p.predrel + (size_t)ah * TFUT_ * 2 + c;
            float* pd = p.pred + (size_t)ah * TFUT_ * 2 + c;
            for (int tt = 0; tt < TFUT_; ++tt) { acc += pr[tt * 2]; pd[tt * 2] = acc; }
        }
    }
}

extern "C" void kernel_launch(void* const* d_in, const int* in_sizes, int n_in,
                              void* d_out, int out_size, void* d_ws, size_t ws_size,
                              hipStream_t stream)
{
    const float* past       = (const float*)d_in[0];
    const float* past_rel   = (const float*)d_in[1];
    const float* ep_w1      = (const float*)d_in[2];
    const float* ep_b1      = (const float*)d_in[3];
    const float* ep_w2      = (const float*)d_in[4];
    const float* ep_b2      = (const float*)d_in[5];
    const float* er_w1      = (const float*)d_in[6];
    const float* er_b1      = (const float*)d_in[7];
    const float* er_w2      = (const float*)d_in[8];
    const float* er_b2      = (const float*)d_in[9];
    const float* enc_wih    = (const float*)d_in[10];
    const float* enc_whh    = (const float*)d_in[11];
    const float* enc_bih    = (const float*)d_in[12];
    const float* enc_bhh    = (const float*)d_in[13];
    const float* rel_wih    = (const float*)d_in[14];
    const float* rel_whh    = (const float*)d_in[15];
    const float* rel_bih    = (const float*)d_in[16];
    const float* rel_bhh    = (const float*)d_in[17];
    const float* dec_wih    = (const float*)d_in[18];
    const float* dec_whh    = (const float*)d_in[19];
    const float* dec_bih    = (const float*)d_in[20];
    const float* dec_bhh    = (const float*)d_in[21];
    const float* out_w      = (const float*)d_in[22];
    const float* out_b      = (const float*)d_in[23];
    const float* read_w     = (const float*)d_in[24];
    const float* read_b     = (const float*)d_in[25];
    const float* write_w    = (const float*)d_in[26];
    const float* write_b    = (const float*)d_in[27];
    const float* init_r     = (const float*)d_in[28];
    const float* h_bias     = (const float*)d_in[29];
    const float* h_rel_bias = (const float*)d_in[30];
    const float* h_fut_bias = (const float*)d_in[31];
    const float* mem_bias   = (const float*)d_in[32];

    float* pred    = (float*)d_out;
    float* predrel = pred + (size_t)A_ * H_ * TFUT_ * 2;

    float* ws = (float*)d_ws;
    size_t off = 0;
    auto alloc = [&](size_t n) { float* p = ws + off; off += n; return p; };
    float* h0     = alloc((size_t)A_ * C_);
    float* h1     = alloc((size_t)A_ * C_);
    float* hr0    = alloc((size_t)A_ * C_);
    float* hr1    = alloc((size_t)A_ * C_);
    float* hf0    = alloc((size_t)H_ * A_ * D_);
    float* hf1    = alloc((size_t)H_ * A_ * D_);
    float* mem    = alloc((size_t)B_ * N_ * M_);
    float* wp     = alloc((size_t)A_ * WP_LD);
    float* rp     = alloc((size_t)A_ * RP_LD);
    float* normsG = alloc((size_t)B_ * N_);

    short* sws = (short*)(ws + off);
    size_t soff = 0;
    auto salloc = [&](size_t n) { short* p = sws + soff; soff += n; return p; };
    short* emb_p_b   = salloc((size_t)TPAST_ * A_ * EMB_);
    short* emb_r_b   = salloc((size_t)TPAST_ * A_ * EMB_);
    short* hb0       = salloc((size_t)A_ * C_);
    short* hb1       = salloc((size_t)A_ * C_);
    short* hrb0      = salloc((size_t)A_ * C_);
    short* hrb1      = salloc((size_t)A_ * C_);
    short* hfb0      = salloc((size_t)H_ * A_ * D_);
    short* hfb1      = salloc((size_t)H_ * A_ * D_);
    short* reads_b   = salloc((size_t)H_ * A_ * M_);
    short* enc_wih_b = salloc((size_t)768 * 160);
    short* enc_whh_b = salloc((size_t)768 * 256);
    short* rel_wih_b = salloc((size_t)768 * 32);
    short* rel_whh_b = salloc((size_t)768 * 256);
    short* dec_wih_b = salloc((size_t)1152 * 384);
    short* dec_whh_b = salloc((size_t)1152 * 384);
    short* write_w_b = salloc((size_t)416 * 256);
    short* read_w_b  = salloc((size_t)672 * 256);
    (void)ws_size; (void)in_sizes; (void)n_in; (void)out_size; (void)past_rel;

    auto cvt = [&](const float* s, short* d, int sr, int sk, int dr, int dk) {
        int total = dr * dk;
        convert_w<<<(total + 255) / 256, 256, 0, stream>>>(s, d, sr, sk, dk, total);
    };
    cvt(enc_wih, enc_wih_b, 768, 144, 768, 160);
    cvt(enc_whh, enc_whh_b, 768, 256, 768, 256);
    cvt(rel_wih, rel_wih_b, 768, 16, 768, 32);
    cvt(rel_whh, rel_whh_b, 768, 256, 768, 256);
    cvt(dec_wih, dec_wih_b, 1152, 384, 1152, 384);
    cvt(dec_whh, dec_whh_b, 1152, 384, 1152, 384);
    cvt(write_w, write_w_b, 385, 256, 416, 256);
    cvt(read_w, read_w_b, 645, 256, 672, 256);

    init_k<<<(B_ * N_ * M_ + 255) / 256, 256, 0, stream>>>(
        h0, h_bias, hb0, hr0, h_rel_bias, hrb0, hf0, h_fut_bias, hfb0,
        reads_b, init_r, mem, normsG, mem_bias);
    embed_k<<<(A_ * TPAST_ + 255) / 256, 256, 0, stream>>>(past, ep_w1, ep_b1, ep_w2, ep_b2, emb_p_b);
    embed_k<<<(A_ * TPAST_ + 255) / 256, 256, 0, stream>>>(past_rel, er_w1, er_b1, er_w2, er_b2, emb_r_b);

    KParams prm;
    prm.enc_wih = enc_wih_b; prm.enc_whh = enc_whh_b;
    prm.rel_wih = rel_wih_b; prm.rel_whh = rel_whh_b;
    prm.dec_wih = dec_wih_b; prm.dec_whh = dec_whh_b;
    prm.write_w = write_w_b; prm.read_w = read_w_b;
    prm.enc_bih = enc_bih; prm.enc_bhh = enc_bhh;
    prm.rel_bih = rel_bih; prm.rel_bhh = rel_bhh;
    prm.dec_bih = dec_bih; prm.dec_bhh = dec_bhh;
    prm.write_b = write_b; prm.read_b = read_b;
    prm.out_w = out_w; prm.out_b = out_b; prm.past = past;
    prm.emb_p = emb_p_b; prm.emb_r = emb_r_b;
    prm.h0 = h0; prm.h1 = h1; prm.hr0 = hr0; prm.hr1 = hr1;
    prm.hf0 = hf0; prm.hf1 = hf1; prm.mem = mem; prm.wp = wp; prm.rp = rp;
    prm.normsG = normsG;
    prm.hb0 = hb0; prm.hb1 = hb1; prm.hrb0 = hrb0; prm.hrb1 = hrb1;
    prm.hfb0 = hfb0; prm.hfb1 = hfb1; prm.reads_b = reads_b;
    prm.pred = pred; prm.predrel = predrel;

    void* args[] = {&prm};
    hipLaunchCooperativeKernel((const void*)model_loop, dim3(256), dim3(512), args, 0, stream);
}

// Round 7
// 10419.191 us; speedup vs baseline: 2.5874x; 2.5874x over previous
//
#include <hip/hip_runtime.h>
#include <math.h>

#define B_    64
#define APER_ 16
#define A_    1024
#define TPAST_ 20
#define TFUT_  30
#define C_    256
#define M_    128
#define N_    256
#define H_    5
#define EMB_  16
#define D_    384
#define TTOT_ 50

typedef short bf16x8 __attribute__((ext_vector_type(8)));
typedef float f32x4 __attribute__((ext_vector_type(4)));

__device__ __forceinline__ float sigmoidf_(float x) { return 1.0f / (1.0f + expf(-x)); }
__device__ __forceinline__ float softplusf_(float x) { return (x > 20.0f) ? x : log1pf(expf(x)); }
__device__ __forceinline__ unsigned short f2bf(float f) {
    unsigned u = __float_as_uint(f);
    return (unsigned short)((u + 0x7FFFu + ((u >> 16) & 1u)) >> 16);
}
__device__ __forceinline__ float bf2f(short s) {
    return __uint_as_float(((unsigned)(unsigned short)s) << 16);
}

// ---------------------------------------------------------------------------
// Prologue: all 8 weight conversions in ONE dispatch (grid-strided segments)
// ---------------------------------------------------------------------------
struct Cvt { const float* src; short* dst; int rows, sk, dk, total; };
struct Cvt8 { Cvt c[8]; };

__global__ __launch_bounds__(256) void convert_all(Cvt8 p)
{
    const int stride = gridDim.x * 256;
    #pragma unroll
    for (int s = 0; s < 8; ++s) {
        const Cvt d = p.c[s];
        for (int idx = blockIdx.x * 256 + threadIdx.x; idx < d.total; idx += stride) {
            const int r = idx / d.dk, k = idx % d.dk;
            float v = (k < d.sk && r < d.rows) ? d.src[(size_t)r * d.sk + k] : 0.f;
            d.dst[idx] = (short)f2bf(v);
        }
    }
}

// Both embedding MLPs in one dispatch
__global__ __launch_bounds__(256) void embed2_k(const float* __restrict__ past, const float* __restrict__ past_rel,
                                                const float* __restrict__ pw1, const float* __restrict__ pb1,
                                                const float* __restrict__ pw2, const float* __restrict__ pb2,
                                                const float* __restrict__ rw1, const float* __restrict__ rb1,
                                                const float* __restrict__ rw2, const float* __restrict__ rb2,
                                                short* __restrict__ emb_p, short* __restrict__ emb_r)
{
    const int idx0 = blockIdx.x * 256 + threadIdx.x;
    const int half = A_ * TPAST_;
    if (idx0 >= 2 * half) return;
    const bool second = idx0 >= half;
    const int idx = second ? idx0 - half : idx0;
    const float* x = second ? past_rel : past;
    const float* w1 = second ? rw1 : pw1; const float* b1 = second ? rb1 : pb1;
    const float* w2 = second ? rw2 : pw2; const float* b2 = second ? rb2 : pb2;
    short* emb = second ? emb_r : emb_p;

    const int a = idx / TPAST_, t = idx % TPAST_;
    const float x0 = x[(size_t)idx * 2], x1 = x[(size_t)idx * 2 + 1];
    float hbuf[8];
    #pragma unroll
    for (int j = 0; j < 8; ++j) hbuf[j] = fmaxf(0.f, w1[j * 2] * x0 + w1[j * 2 + 1] * x1 + b1[j]);
    short* e = emb + ((size_t)t * A_ + a) * EMB_;
    #pragma unroll
    for (int i = 0; i < 16; ++i) {
        float acc = b2[i];
        #pragma unroll
        for (int j = 0; j < 8; ++j) acc += w2[i * 8 + j] * hbuf[j];
        e[i] = (short)f2bf(acc);
    }
}

__global__ __launch_bounds__(256) void init_k(float* __restrict__ h, const float* __restrict__ h_bias, short* __restrict__ hb,
                                              float* __restrict__ hr, const float* __restrict__ hr_bias, short* __restrict__ hrb,
                                              float* __restrict__ hf, const float* __restrict__ hf_bias, short* __restrict__ hfb,
                                              short* __restrict__ reads_b, const float* __restrict__ init_r,
                                              float* __restrict__ mem,
                                              float* __restrict__ normsG, const float* __restrict__ mem_bias)
{
    const int idx = blockIdx.x * 256 + threadIdx.x;
    if (idx < B_ * N_ * M_) mem[idx] = mem_bias[idx & (N_ * M_ - 1)];
    if (idx < B_ * N_) {
        const float* r = mem_bias + (size_t)(idx & (N_ - 1)) * M_;
        float ss = 0.f;
        for (int k = 0; k < M_; ++k) ss += r[k] * r[k];
        normsG[idx] = sqrtf(ss) + 1e-16f;
    }
    if (idx < A_ * C_) {
        float v = h_bias[idx & (C_ - 1)];
        h[idx] = v; hb[idx] = (short)f2bf(v);
        v = hr_bias[idx & (C_ - 1)];
        hr[idx] = v; hrb[idx] = (short)f2bf(v);
    }
    if (idx < H_ * A_ * D_) {
        float v = hf_bias[idx % D_];
        hf[idx] = v; hfb[idx] = (short)f2bf(v);
    }
    if (idx < A_ * M_) reads_b[idx] = (short)f2bf(init_r[idx & (M_ - 1)]);
}

// ---------------------------------------------------------------------------
// GRU tile (proven round-5 math, verbatim). One wave = 32x32 output tile.
// ---------------------------------------------------------------------------
__device__ __forceinline__ void gru_tile(
    const short* __restrict__ X1, int K1,
    const short* __restrict__ X2, int K2,
    const short* __restrict__ Wih, int Kpad,
    const float* __restrict__ bih,
    const short* __restrict__ Hb, const short* __restrict__ Whh,
    const float* __restrict__ bhh,
    const float* __restrict__ Hprev,
    float* __restrict__ Hnew, short* __restrict__ Hnewb,
    int G, int rowBase, int colBase, int lane)
{
    const int l16 = lane & 15;
    const int kb8 = (lane >> 4) * 8;

    f32x4 gi[3][2][2], gh[3][2][2];
    const f32x4 z4 = {0.f, 0.f, 0.f, 0.f};
    #pragma unroll
    for (int g = 0; g < 3; ++g)
        #pragma unroll
        for (int i = 0; i < 2; ++i)
            #pragma unroll
            for (int j = 0; j < 2; ++j) { gi[g][i][j] = z4; gh[g][i][j] = z4; }

    for (int kc = 0; kc < Kpad; kc += 32) {
        bf16x8 afr[2];
        const int k8 = kc + kb8;
        #pragma unroll
        for (int i = 0; i < 2; ++i) {
            const int r = rowBase + i * 16 + l16;
            bf16x8 v = {0, 0, 0, 0, 0, 0, 0, 0};
            if (k8 < K1) {
                if (X1) v = *(const bf16x8*)(X1 + (size_t)(r & 1023) * K1 + k8);
            } else if (k8 < K1 + K2) {
                v = *(const bf16x8*)(X2 + (size_t)r * K2 + (k8 - K1));
            }
            afr[i] = v;
        }
        #pragma unroll
        for (int g = 0; g < 3; ++g)
            #pragma unroll
            for (int j = 0; j < 2; ++j) {
                const bf16x8 b = *(const bf16x8*)(Wih + (size_t)(g * G + colBase + j * 16 + l16) * Kpad + k8);
                gi[g][0][j] = __builtin_amdgcn_mfma_f32_16x16x32_bf16(afr[0], b, gi[g][0][j], 0, 0, 0);
                gi[g][1][j] = __builtin_amdgcn_mfma_f32_16x16x32_bf16(afr[1], b, gi[g][1][j], 0, 0, 0);
            }
    }
    for (int kc = 0; kc < G; kc += 32) {
        const int k8 = kc + kb8;
        bf16x8 afr[2];
        #pragma unroll
        for (int i = 0; i < 2; ++i)
            afr[i] = *(const bf16x8*)(Hb + (size_t)(rowBase + i * 16 + l16) * G + k8);
        #pragma unroll
        for (int g = 0; g < 3; ++g)
            #pragma unroll
            for (int j = 0; j < 2; ++j) {
                const bf16x8 b = *(const bf16x8*)(Whh + (size_t)(g * G + colBase + j * 16 + l16) * G + k8);
                gh[g][0][j] = __builtin_amdgcn_mfma_f32_16x16x32_bf16(afr[0], b, gh[g][0][j], 0, 0, 0);
                gh[g][1][j] = __builtin_amdgcn_mfma_f32_16x16x32_bf16(afr[1], b, gh[g][1][j], 0, 0, 0);
            }
    }

    const int r4 = (lane >> 4) * 4;
    #pragma unroll
    for (int j = 0; j < 2; ++j) {
        const int col = colBase + j * 16 + l16;
        const float bi0 = bih[col],         bh0 = bhh[col];
        const float bi1 = bih[G + col],     bh1 = bhh[G + col];
        const float bi2 = bih[2 * G + col], bh2 = bhh[2 * G + col];
        #pragma unroll
        for (int i = 0; i < 2; ++i) {
            #pragma unroll
            for (int q = 0; q < 4; ++q) {
                const int row = rowBase + i * 16 + r4 + q;
                const float rr = sigmoidf_(gi[0][i][j][q] + bi0 + gh[0][i][j][q] + bh0);
                const float zz = sigmoidf_(gi[1][i][j][q] + bi1 + gh[1][i][j][q] + bh1);
                const float nn = tanhf(gi[2][i][j][q] + bi2 + rr * (gh[2][i][j][q] + bh2));
                const float hp = Hprev[(size_t)row * G + col];
                const float hv = (1.f - zz) * nn + zz * hp;
                Hnew[(size_t)row * G + col] = hv;
                Hnewb[(size_t)row * G + col] = (short)f2bf(hv);
            }
        }
    }
}

// ---------------------------------------------------------------------------
// phaseA: enc-GRU(t) | rel-GRU(t) | deferred dec-GRU(t-1).
// 256-thread blocks, 4 tiles (waves) per block. dec = blocks beyond enc+rel.
// ---------------------------------------------------------------------------
__global__ __launch_bounds__(256) void phaseA(
    const short* __restrict__ ep, const short* __restrict__ er,
    const short* __restrict__ enc_wih, const float* __restrict__ enc_bih,
    const short* __restrict__ enc_whh, const float* __restrict__ enc_bhh,
    const short* __restrict__ rel_wih, const float* __restrict__ rel_bih,
    const short* __restrict__ rel_whh, const float* __restrict__ rel_bhh,
    const short* __restrict__ dec_wih, const float* __restrict__ dec_bih,
    const short* __restrict__ dec_whh, const float* __restrict__ dec_bhh,
    const float* __restrict__ hc, const short* __restrict__ hbc,
    float* __restrict__ hn, short* __restrict__ hbn,
    const float* __restrict__ hrc, const short* __restrict__ hrbc,
    float* __restrict__ hrn, short* __restrict__ hrbn,
    const float* __restrict__ hfc, const short* __restrict__ hfbc,
    float* __restrict__ hfn, short* __restrict__ hfbn,
    const short* __restrict__ reads_b,
    int encBlocks, int relBlocks)
{
    const int bid = blockIdx.x;
    const int wave = threadIdx.x >> 6;
    const int lane = threadIdx.x & 63;

    if (bid < encBlocks) {
        const int tile = bid * 4 + wave;                  // 256 tiles: 32 row x 8 col
        gru_tile(ep, 16, reads_b, 128, enc_wih, 160, enc_bih,
                 hbc, enc_whh, enc_bhh, hc, hn, hbn, C_,
                 (tile >> 3) * 32, (tile & 7) * 32, lane);
    } else if (bid < encBlocks + relBlocks) {
        const int tile = (bid - encBlocks) * 4 + wave;
        gru_tile(er, 16, nullptr, 0, rel_wih, 32, rel_bih,
                 hrbc, rel_whh, rel_bhh, hrc, hrn, hrbn, C_,
                 (tile >> 3) * 32, (tile & 7) * 32, lane);
    } else {
        const int tile = (bid - encBlocks - relBlocks) * 4 + wave;  // 1920: 160 row x 12 col
        gru_tile(hbc, 256, reads_b, 128, dec_wih, 384, dec_bih,
                 hfbc, dec_whh, dec_bhh, hfc, hfn, hfbn, D_,
                 (tile / 12) * 32, (tile % 12) * 32, lane);
    }
}

// ---------------------------------------------------------------------------
// phaseB: per-agent [write-head GEMV (LDS) + NTM write + norms] | out(t-1).
// ---------------------------------------------------------------------------
__global__ __launch_bounds__(256) void phaseB(
    const short* __restrict__ hbn, const short* __restrict__ write_w_b,
    const float* __restrict__ write_b,
    float* __restrict__ mem, float* __restrict__ normsG,
    const float* __restrict__ hfn, const float* __restrict__ out_w,
    const float* __restrict__ out_b, float* __restrict__ predrel,
    int outT, int agentBlocks)
{
    __shared__ float wl[388];
    __shared__ __align__(16) short xs[256];
    __shared__ float kw[128], er[128], ad[128], red[256], ww[16], logit[16];
    __shared__ float buf[2048];
    __shared__ float beta_s, knorm_s;
    const int tid = threadIdx.x;

    if ((int)blockIdx.x >= agentBlocks) {
        // ---- out projection path: 8-lane groups, 8 rows per wave ----
        const int widx = ((int)blockIdx.x - agentBlocks) * 4 + (tid >> 6);
        const int lane = tid & 63;
        const int g = lane >> 3, li = lane & 7;
        const int row = widx * 8 + g;                     // < 5120
        const float* hrow = hfn + (size_t)row * D_;
        float a0 = 0.f, a1 = 0.f;
        for (int k = li; k < D_; k += 8) {
            const float v = hrow[k];
            a0 += v * out_w[k];
            a1 += v * out_w[D_ + k];
        }
        a0 += __shfl_xor(a0, 1); a0 += __shfl_xor(a0, 2); a0 += __shfl_xor(a0, 4);
        a1 += __shfl_xor(a1, 1); a1 += __shfl_xor(a1, 2); a1 += __shfl_xor(a1, 4);
        if (li == 0) {
            const int hh = row >> 10, aa = row & 1023;
            float* o = predrel + (((size_t)aa * H_ + hh) * TFUT_ + outT) * 2;
            o[0] = a0 + out_b[0];
            o[1] = a1 + out_b[1];
        }
        return;
    }

    const int a = blockIdx.x;
    const int b = a >> 4, p = a & 15;

    // stage h(t) row (bf16) then GEMV wp = h @ write_w^T + b into LDS
    if (tid < 32) ((bf16x8*)xs)[tid] = ((const bf16x8*)(hbn + (size_t)a * C_))[tid];
    __syncthreads();
    for (int c = tid; c < 385; c += 256) {
        const short* wr = write_w_b + (size_t)c * 256;
        float acc = write_b[c];
        for (int k = 0; k < 256; k += 8) {
            const bf16x8 wv = *(const bf16x8*)(wr + k);
            const bf16x8 xv = *(const bf16x8*)(xs + k);
            #pragma unroll
            for (int r = 0; r < 8; ++r) acc = fmaf(bf2f(xv[r]), bf2f(wv[r]), acc);
        }
        wl[c] = acc;
    }
    __syncthreads();

    // ---- round-5 write body (w -> wl) ----
    if (tid < 128) {
        kw[tid] = tanhf(wl[tid]);
        er[tid] = sigmoidf_(wl[129 + tid]);
        ad[tid] = tanhf(wl[257 + tid]);
    }
    if (tid == 0) beta_s = softplusf_(wl[128]);
    __syncthreads();

    red[tid] = (tid < 128) ? kw[tid] * kw[tid] : 0.f;
    __syncthreads();
    for (int s = 128; s > 0; s >>= 1) { if (tid < s) red[tid] += red[tid + s]; __syncthreads(); }
    if (tid == 0) knorm_s = sqrtf(red[0]) + 1e-16f;
    __syncthreads();

    const int s = tid >> 4, j = tid & 15;
    float dot = 0.f, ss = 0.f;
    {
        const float* mrow = mem + ((size_t)(b * N_) + p * 16 + s) * M_;
        for (int k = j; k < 128; k += 16) { float v = mrow[k]; dot += kw[k] * v; ss += v * v; }
    }
    red[tid] = dot; __syncthreads();
    for (int st = 8; st > 0; st >>= 1) { if (j < st) red[tid] += red[tid + st]; __syncthreads(); }
    float dotf = red[s * 16];
    __syncthreads();
    red[tid] = ss; __syncthreads();
    for (int st = 8; st > 0; st >>= 1) { if (j < st) red[tid] += red[tid + st]; __syncthreads(); }
    float ssf = red[s * 16];
    if (j == 0) {
        float mn = sqrtf(ssf) + 1e-16f;
        logit[s] = beta_s * (dotf / (mn * knorm_s));
    }
    __syncthreads();
    if (tid == 0) {
        float mx = -1e30f;
        for (int i = 0; i < 16; ++i) mx = fmaxf(mx, logit[i]);
        float sum = 0.f;
        for (int i = 0; i < 16; ++i) { float e = __expf(logit[i] - mx); ww[i] = e; sum += e; }
        float inv = 1.f / sum;
        for (int i = 0; i < 16; ++i) ww[i] *= inv;
    }
    __syncthreads();
    for (int idx = tid; idx < 16 * 128; idx += 256) {
        int si = idx >> 7, m = idx & 127;
        size_t g = ((size_t)(b * N_) + p * 16 + si) * M_ + m;
        float wwv = ww[si];
        float v = mem[g] * (1.f - wwv * er[m]) + wwv * ad[m];
        mem[g] = v;
        buf[idx] = v;
    }
    __syncthreads();
    {
        float ssq = 0.f;
        #pragma unroll
        for (int i = 0; i < 8; ++i) { float v = buf[s * 128 + j + 16 * i]; ssq += v * v; }
        #pragma unroll
        for (int m = 1; m < 16; m <<= 1) ssq += __shfl_xor(ssq, m);
        if (j == 0) normsG[b * N_ + p * 16 + s] = sqrtf(ssq) + 1e-16f;
    }
}

// ---------------------------------------------------------------------------
// phaseC: per-(scene,head) [read-head GEMV (fused) + sims MFMA + softmax + PV]
// ---------------------------------------------------------------------------
__global__ __launch_bounds__(256) void phaseC(
    const short* __restrict__ hrbn, const short* __restrict__ read_w_b,
    const float* __restrict__ read_b,
    const float* __restrict__ mem, const float* __restrict__ normsG,
    short* __restrict__ reads_b)
{
    const int task = blockIdx.x;          // 320 = H*B
    const int h = task >> 6, b = task & 63;
    __shared__ __align__(16) short xs[16 * 256];
    __shared__ __align__(16) float kq[16 * 132];
    __shared__ float S[16 * 260];
    __shared__ float beta_s[16], knorm_s[16], inv_s[16];
    const int tid = threadIdx.x;

    // stage hr(t) rows for this scene (16 x 256 bf16)
    {
        const bf16x8* src = (const bf16x8*)(hrbn + (size_t)(b * 16) * C_);
        ((bf16x8*)xs)[tid] = src[tid];
        ((bf16x8*)xs)[tid + 256] = src[tid + 256];
    }
    __syncthreads();

    // rp GEMV (+tanh / softplus) into kq / beta_s
    for (int o = tid; o < 16 * 129; o += 256) {
        const int a = o / 129, c = o % 129;
        const short* wr = read_w_b + (size_t)(h * 129 + c) * 256;
        const short* xr = xs + a * 256;
        float acc = read_b[h * 129 + c];
        for (int k = 0; k < 256; k += 8) {
            const bf16x8 wv = *(const bf16x8*)(wr + k);
            const bf16x8 xv = *(const bf16x8*)(xr + k);
            #pragma unroll
            for (int r = 0; r < 8; ++r) acc = fmaf(bf2f(xv[r]), bf2f(wv[r]), acc);
        }
        if (c < 128) kq[a * 132 + c] = tanhf(acc);
        else beta_s[a] = softplusf_(acc);
    }
    __syncthreads();

    // per-agent key norms
    {
        const int a = tid >> 4, sub = tid & 15;
        float ssk = 0.f;
        #pragma unroll
        for (int i = 0; i < 8; ++i) { const float v = kq[a * 132 + sub + 16 * i]; ssk += v * v; }
        #pragma unroll
        for (int m = 1; m < 16; m <<= 1) ssk += __shfl_xor(ssk, m);
        if (sub == 0) knorm_s[a] = sqrtf(ssk) + 1e-16f;
    }
    __syncthreads();

    // sims via hi/lo compensated MFMA (full 256-slot coverage: 4 waves x 4 sub-tiles)
    {
        const int wave = tid >> 6, lane = tid & 63;
        const int l16 = lane & 15, kb8 = (lane >> 4) * 8;
        const int slotBase = wave * 64;
        const f32x4 z4 = {0.f, 0.f, 0.f, 0.f};
        f32x4 acc[4] = {z4, z4, z4, z4};
        const float* mb = mem + (size_t)b * N_ * M_;
        #pragma unroll
        for (int kc = 0; kc < 128; kc += 32) {
            const float* ap = kq + l16 * 132 + kc + kb8;
            bf16x8 ah, al;
            #pragma unroll
            for (int r = 0; r < 8; ++r) {
                const float av = ap[r];
                const short hv = (short)f2bf(av);
                ah[r] = hv; al[r] = (short)f2bf(av - bf2f(hv));
            }
            #pragma unroll
            for (int tt = 0; tt < 4; ++tt) {
                const float* bp = mb + (size_t)(slotBase + tt * 16 + l16) * M_ + kc + kb8;
                bf16x8 bh, bl;
                #pragma unroll
                for (int r = 0; r < 8; ++r) {
                    const float bv = bp[r];
                    const short hv = (short)f2bf(bv);
                    bh[r] = hv; bl[r] = (short)f2bf(bv - bf2f(hv));
                }
                acc[tt] = __builtin_amdgcn_mfma_f32_16x16x32_bf16(ah, bh, acc[tt], 0, 0, 0);
                acc[tt] = __builtin_amdgcn_mfma_f32_16x16x32_bf16(ah, bl, acc[tt], 0, 0, 0);
                acc[tt] = __builtin_amdgcn_mfma_f32_16x16x32_bf16(al, bh, acc[tt], 0, 0, 0);
            }
        }
        const int r4 = (lane >> 4) * 4;
        #pragma unroll
        for (int tt = 0; tt < 4; ++tt) {
            const int slot = slotBase + tt * 16 + l16;
            const float nv = normsG[b * N_ + slot];
            #pragma unroll
            for (int q = 0; q < 4; ++q) {
                const int aq = r4 + q;
                const float lg = ((slot >> 4) == aq) ? -1e30f
                               : beta_s[aq] * acc[tt][q] / (nv * knorm_s[aq]);
                S[aq * 260 + slot] = lg;
            }
        }
    }
    __syncthreads();

    // per-agent masked softmax over 256 slots
    {
        const int a = tid >> 4, sub = tid & 15;
        float mx = -1e30f;
        #pragma unroll
        for (int i = 0; i < 16; ++i) mx = fmaxf(mx, S[a * 260 + sub + 16 * i]);
        #pragma unroll
        for (int m = 1; m < 16; m <<= 1) mx = fmaxf(mx, __shfl_xor(mx, m));
        float e[16]; float sum = 0.f;
        #pragma unroll
        for (int i = 0; i < 16; ++i) { e[i] = __expf(S[a * 260 + sub + 16 * i] - mx); sum += e[i]; }
        #pragma unroll
        for (int i = 0; i < 16; ++i) S[a * 260 + sub + 16 * i] = e[i];
        #pragma unroll
        for (int m = 1; m < 16; m <<= 1) sum += __shfl_xor(sum, m);
        if (sub == 0) inv_s[a] = 1.f / sum;
    }
    __syncthreads();

    // PV fp32
    {
        const int a = tid >> 4, sub = tid & 15;
        const int m0 = sub * 8;
        const float* mb = mem + (size_t)b * N_ * M_ + m0;
        float acc[8];
        #pragma unroll
        for (int r = 0; r < 8; ++r) acc[r] = 0.f;
        const float* Sa = S + a * 260;
        #pragma unroll 4
        for (int n = 0; n < N_; ++n) {
            const float w = Sa[n];
            const float4 v0 = *(const float4*)(mb + (size_t)n * M_);
            const float4 v1 = *(const float4*)(mb + (size_t)n * M_ + 4);
            acc[0] = fmaf(w, v0.x, acc[0]); acc[1] = fmaf(w, v0.y, acc[1]);
            acc[2] = fmaf(w, v0.z, acc[2]); acc[3] = fmaf(w, v0.w, acc[3]);
            acc[4] = fmaf(w, v1.x, acc[4]); acc[5] = fmaf(w, v1.y, acc[5]);
            acc[6] = fmaf(w, v1.z, acc[6]); acc[7] = fmaf(w, v1.w, acc[7]);
        }
        const float inv = inv_s[a];
        short pk[8];
        #pragma unroll
        for (int r = 0; r < 8; ++r) pk[r] = (short)f2bf(acc[r] * inv);
        *(bf16x8*)(reads_b + ((size_t)h * A_ + b * 16 + a) * M_ + m0) = *(bf16x8*)pk;
    }
}

__global__ __launch_bounds__(256) void cumsum_k(const float* __restrict__ past,
                                                const float* __restrict__ predrel,
                                                float* __restrict__ pred)
{
    const int idx = blockIdx.x * 256 + threadIdx.x;
    if (idx >= A_ * H_ * 2) return;
    const int c = idx & 1;
    const int ah = idx >> 1;
    const int a = ah / H_;
    float acc = past[((size_t)a * TPAST_ + TPAST_ - 1) * 2 + c];
    const float* pr = predrel + (size_t)ah * TFUT_ * 2 + c;
    float* pd = pred + (size_t)ah * TFUT_ * 2 + c;
    for (int t = 0; t < TFUT_; ++t) { acc += pr[t * 2]; pd[t * 2] = acc; }
}

extern "C" void kernel_launch(void* const* d_in, const int* in_sizes, int n_in,
                              void* d_out, int out_size, void* d_ws, size_t ws_size,
                              hipStream_t stream)
{
    const float* past       = (const float*)d_in[0];
    const float* past_rel   = (const float*)d_in[1];
    const float* ep_w1      = (const float*)d_in[2];
    const float* ep_b1      = (const float*)d_in[3];
    const float* ep_w2      = (const float*)d_in[4];
    const float* ep_b2      = (const float*)d_in[5];
    const float* er_w1      = (const float*)d_in[6];
    const float* er_b1      = (const float*)d_in[7];
    const float* er_w2      = (const float*)d_in[8];
    const float* er_b2      = (const float*)d_in[9];
    const float* enc_wih    = (const float*)d_in[10];
    const float* enc_whh    = (const float*)d_in[11];
    const float* enc_bih    = (const float*)d_in[12];
    const float* enc_bhh    = (const float*)d_in[13];
    const float* rel_wih    = (const float*)d_in[14];
    const float* rel_whh    = (const float*)d_in[15];
    const float* rel_bih    = (const float*)d_in[16];
    const float* rel_bhh    = (const float*)d_in[17];
    const float* dec_wih    = (const float*)d_in[18];
    const float* dec_whh    = (const float*)d_in[19];
    const float* dec_bih    = (const float*)d_in[20];
    const float* dec_bhh    = (const float*)d_in[21];
    const float* out_w      = (const float*)d_in[22];
    const float* out_b      = (const float*)d_in[23];
    const float* read_w     = (const float*)d_in[24];
    const float* read_b     = (const float*)d_in[25];
    const float* write_w    = (const float*)d_in[26];
    const float* write_b    = (const float*)d_in[27];
    const float* init_r     = (const float*)d_in[28];
    const float* h_bias     = (const float*)d_in[29];
    const float* h_rel_bias = (const float*)d_in[30];
    const float* h_fut_bias = (const float*)d_in[31];
    const float* mem_bias   = (const float*)d_in[32];

    float* pred    = (float*)d_out;
    float* predrel = pred + (size_t)A_ * H_ * TFUT_ * 2;

    float* ws = (float*)d_ws;
    size_t off = 0;
    auto alloc = [&](size_t n) { float* p = ws + off; off += n; return p; };
    float* h0     = alloc((size_t)A_ * C_);
    float* h1     = alloc((size_t)A_ * C_);
    float* hr0    = alloc((size_t)A_ * C_);
    float* hr1    = alloc((size_t)A_ * C_);
    float* hf0    = alloc((size_t)H_ * A_ * D_);
    float* hf1    = alloc((size_t)H_ * A_ * D_);
    float* mem    = alloc((size_t)B_ * N_ * M_);
    float* normsG = alloc((size_t)B_ * N_);

    short* sws = (short*)(ws + off);
    size_t soff = 0;
    auto salloc = [&](size_t n) { short* p = sws + soff; soff += n; return p; };
    short* emb_p_b   = salloc((size_t)TPAST_ * A_ * EMB_);
    short* emb_r_b   = salloc((size_t)TPAST_ * A_ * EMB_);
    short* hb0       = salloc((size_t)A_ * C_);
    short* hb1       = salloc((size_t)A_ * C_);
    short* hrb0      = salloc((size_t)A_ * C_);
    short* hrb1      = salloc((size_t)A_ * C_);
    short* hfb0      = salloc((size_t)H_ * A_ * D_);
    short* hfb1      = salloc((size_t)H_ * A_ * D_);
    short* reads_b   = salloc((size_t)H_ * A_ * M_);
    short* enc_wih_b = salloc((size_t)768 * 160);
    short* enc_whh_b = salloc((size_t)768 * 256);
    short* rel_wih_b = salloc((size_t)768 * 32);
    short* rel_whh_b = salloc((size_t)768 * 256);
    short* dec_wih_b = salloc((size_t)1152 * 384);
    short* dec_whh_b = salloc((size_t)1152 * 384);
    short* write_w_b = salloc((size_t)385 * 256);
    short* read_w_b  = salloc((size_t)645 * 256);
    (void)ws_size; (void)in_sizes; (void)n_in; (void)out_size;

    // prologue (3 dispatches)
    Cvt8 cp;
    cp.c[0] = {enc_wih, enc_wih_b, 768, 144, 160, 768 * 160};
    cp.c[1] = {enc_whh, enc_whh_b, 768, 256, 256, 768 * 256};
    cp.c[2] = {rel_wih, rel_wih_b, 768, 16, 32, 768 * 32};
    cp.c[3] = {rel_whh, rel_whh_b, 768, 256, 256, 768 * 256};
    cp.c[4] = {dec_wih, dec_wih_b, 1152, 384, 384, 1152 * 384};
    cp.c[5] = {dec_whh, dec_whh_b, 1152, 384, 384, 1152 * 384};
    cp.c[6] = {write_w, write_w_b, 385, 256, 256, 385 * 256};
    cp.c[7] = {read_w, read_w_b, 645, 256, 256, 645 * 256};
    convert_all<<<1024, 256, 0, stream>>>(cp);

    init_k<<<(B_ * N_ * M_ + 255) / 256, 256, 0, stream>>>(
        h0, h_bias, hb0, hr0, h_rel_bias, hrb0, hf0, h_fut_bias, hfb0,
        reads_b, init_r, mem, normsG, mem_bias);
    embed2_k<<<(2 * A_ * TPAST_ + 255) / 256, 256, 0, stream>>>(
        past, past_rel, ep_w1, ep_b1, ep_w2, ep_b2, er_w1, er_b1, er_w2, er_b2,
        emb_p_b, emb_r_b);

    float *hc = h0, *hn = h1, *hrc = hr0, *hrn = hr1, *hfc = hf0, *hfn = hf1;
    short *hbc = hb0, *hbn = hb1, *hrbc = hrb0, *hrbn = hrb1, *hfbc = hfb0, *hfbn = hfb1;

    for (int t = 0; t < TTOT_; ++t) {
        const short* ep = (t < TPAST_) ? emb_p_b + (size_t)t * A_ * EMB_ : nullptr;
        const short* er = (t < TPAST_) ? emb_r_b + (size_t)t * A_ * EMB_ : nullptr;

        // phase A: enc(t) + rel(t) + dec(t-1)   [dec only when t>=1]
        const int gridA = (t == 0) ? 128 : 608;
        phaseA<<<gridA, 256, 0, stream>>>(
            ep, er,
            enc_wih_b, enc_bih, enc_whh_b, enc_bhh,
            rel_wih_b, rel_bih, rel_whh_b, rel_bhh,
            dec_wih_b, dec_bih, dec_whh_b, dec_bhh,
            hc, hbc, hn, hbn,
            hrc, hrbc, hrn, hrbn,
            hfc, hfbc, hfn, hfbn,
            reads_b, 64, 64);

        // phase B: write(t) + out(t-1) when t>=21
        const int gridB = (t >= 21) ? 1184 : 1024;
        phaseB<<<gridB, 256, 0, stream>>>(
            hbn, write_w_b, write_b, mem, normsG,
            hfn, out_w, out_b, predrel, t - 21, 1024);

        // phase C: read(t)
        phaseC<<<320, 256, 0, stream>>>(hrbn, read_w_b, read_b, mem, normsG, reads_b);

        // swap h/hr every step; hf only when dec actually ran
        float* tf; short* ts;
        tf = hc; hc = hn; hn = tf;       ts = hbc; hbc = hbn; hbn = ts;
        tf = hrc; hrc = hrn; hrn = tf;   ts = hrbc; hrbc = hrbn; hrbn = ts;
        if (t >= 1) {
            tf = hfc; hfc = hfn; hfn = tf;  ts = hfbc; hfbc = hfbn; hfbn = ts;
        }
    }

    // epilogue: dec(49), out(49), cumsum
    phaseA<<<480, 256, 0, stream>>>(
        nullptr, nullptr,
        enc_wih_b, enc_bih, enc_whh_b, enc_bhh,
        rel_wih_b, rel_bih, rel_whh_b, rel_bhh,
        dec_wih_b, dec_bih, dec_whh_b, dec_bhh,
        hc, hbc, hn, hbn,
        hrc, hrbc, hrn, hrbn,
        hfc, hfbc, hfn, hfbn,
        reads_b, 0, 0);
    phaseB<<<160, 256, 0, stream>>>(
        hbn, write_w_b, write_b, mem, normsG,
        hfn, out_w, out_b, predrel, TFUT_ - 1, 0);
    cumsum_k<<<(A_ * H_ * 2 + 255) / 256, 256, 0, stream>>>(past, predrel, pred);
}

// Round 8
// 7220.355 us; speedup vs baseline: 3.7337x; 1.4430x over previous
//
#include <hip/hip_runtime.h>
#include <math.h>

#define B_    64
#define APER_ 16
#define A_    1024
#define TPAST_ 20
#define TFUT_  30
#define C_    256
#define M_    128
#define N_    256
#define H_    5
#define EMB_  16
#define D_    384
#define TTOT_ 50

typedef short bf16x8 __attribute__((ext_vector_type(8)));
typedef float f32x4 __attribute__((ext_vector_type(4)));

__device__ __forceinline__ float sigmoidf_(float x) { return 1.0f / (1.0f + expf(-x)); }
__device__ __forceinline__ float softplusf_(float x) { return (x > 20.0f) ? x : log1pf(expf(x)); }
__device__ __forceinline__ unsigned short f2bf(float f) {
    unsigned u = __float_as_uint(f);
    return (unsigned short)((u + 0x7FFFu + ((u >> 16) & 1u)) >> 16);
}
__device__ __forceinline__ float bf2f(short s) {
    return __uint_as_float(((unsigned)(unsigned short)s) << 16);
}

// ---------------------------------------------------------------------------
// Prologue: all 8 weight conversions in ONE dispatch (grid-strided segments)
// ---------------------------------------------------------------------------
struct Cvt { const float* src; short* dst; int rows, sk, dk, total; };
struct Cvt8 { Cvt c[8]; };

__global__ __launch_bounds__(256) void convert_all(Cvt8 p)
{
    const int stride = gridDim.x * 256;
    #pragma unroll
    for (int s = 0; s < 8; ++s) {
        const Cvt d = p.c[s];
        for (int idx = blockIdx.x * 256 + threadIdx.x; idx < d.total; idx += stride) {
            const int r = idx / d.dk, k = idx % d.dk;
            float v = (k < d.sk && r < d.rows) ? d.src[(size_t)r * d.sk + k] : 0.f;
            d.dst[idx] = (short)f2bf(v);
        }
    }
}

__global__ __launch_bounds__(256) void embed2_k(const float* __restrict__ past, const float* __restrict__ past_rel,
                                                const float* __restrict__ pw1, const float* __restrict__ pb1,
                                                const float* __restrict__ pw2, const float* __restrict__ pb2,
                                                const float* __restrict__ rw1, const float* __restrict__ rb1,
                                                const float* __restrict__ rw2, const float* __restrict__ rb2,
                                                short* __restrict__ emb_p, short* __restrict__ emb_r)
{
    const int idx0 = blockIdx.x * 256 + threadIdx.x;
    const int half = A_ * TPAST_;
    if (idx0 >= 2 * half) return;
    const bool second = idx0 >= half;
    const int idx = second ? idx0 - half : idx0;
    const float* x = second ? past_rel : past;
    const float* w1 = second ? rw1 : pw1; const float* b1 = second ? rb1 : pb1;
    const float* w2 = second ? rw2 : pw2; const float* b2 = second ? rb2 : pb2;
    short* emb = second ? emb_r : emb_p;

    const int a = idx / TPAST_, t = idx % TPAST_;
    const float x0 = x[(size_t)idx * 2], x1 = x[(size_t)idx * 2 + 1];
    float hbuf[8];
    #pragma unroll
    for (int j = 0; j < 8; ++j) hbuf[j] = fmaxf(0.f, w1[j * 2] * x0 + w1[j * 2 + 1] * x1 + b1[j]);
    short* e = emb + ((size_t)t * A_ + a) * EMB_;
    #pragma unroll
    for (int i = 0; i < 16; ++i) {
        float acc = b2[i];
        #pragma unroll
        for (int j = 0; j < 8; ++j) acc += w2[i * 8 + j] * hbuf[j];
        e[i] = (short)f2bf(acc);
    }
}

__global__ __launch_bounds__(256) void init_k(float* __restrict__ h, const float* __restrict__ h_bias, short* __restrict__ hb,
                                              float* __restrict__ hr, const float* __restrict__ hr_bias, short* __restrict__ hrb,
                                              float* __restrict__ hf, const float* __restrict__ hf_bias, short* __restrict__ hfb,
                                              short* __restrict__ reads_b, const float* __restrict__ init_r,
                                              float* __restrict__ mem, short* __restrict__ memhi, short* __restrict__ memlo,
                                              float* __restrict__ normsG, const float* __restrict__ mem_bias)
{
    const int idx = blockIdx.x * 256 + threadIdx.x;
    if (idx < B_ * N_ * M_) {
        const float v = mem_bias[idx & (N_ * M_ - 1)];
        mem[idx] = v;
        const short hv = (short)f2bf(v);
        memhi[idx] = hv;
        memlo[idx] = (short)f2bf(v - bf2f(hv));
    }
    if (idx < B_ * N_) {
        const float* r = mem_bias + (size_t)(idx & (N_ - 1)) * M_;
        float ss = 0.f;
        for (int k = 0; k < M_; ++k) ss += r[k] * r[k];
        normsG[idx] = sqrtf(ss) + 1e-16f;
    }
    if (idx < A_ * C_) {
        float v = h_bias[idx & (C_ - 1)];
        h[idx] = v; hb[idx] = (short)f2bf(v);
        v = hr_bias[idx & (C_ - 1)];
        hr[idx] = v; hrb[idx] = (short)f2bf(v);
    }
    if (idx < H_ * A_ * D_) {
        float v = hf_bias[idx % D_];
        hf[idx] = v; hfb[idx] = (short)f2bf(v);
    }
    if (idx < A_ * M_) reads_b[idx] = (short)f2bf(init_r[idx & (M_ - 1)]);
}

// ---------------------------------------------------------------------------
// GRU tile (proven round-5 math, verbatim). One wave = 32x32 output tile.
// ---------------------------------------------------------------------------
__device__ __forceinline__ void gru_tile(
    const short* __restrict__ X1, int K1,
    const short* __restrict__ X2, int K2,
    const short* __restrict__ Wih, int Kpad,
    const float* __restrict__ bih,
    const short* __restrict__ Hb, const short* __restrict__ Whh,
    const float* __restrict__ bhh,
    const float* __restrict__ Hprev,
    float* __restrict__ Hnew, short* __restrict__ Hnewb,
    int G, int rowBase, int colBase, int lane)
{
    const int l16 = lane & 15;
    const int kb8 = (lane >> 4) * 8;

    f32x4 gi[3][2][2], gh[3][2][2];
    const f32x4 z4 = {0.f, 0.f, 0.f, 0.f};
    #pragma unroll
    for (int g = 0; g < 3; ++g)
        #pragma unroll
        for (int i = 0; i < 2; ++i)
            #pragma unroll
            for (int j = 0; j < 2; ++j) { gi[g][i][j] = z4; gh[g][i][j] = z4; }

    for (int kc = 0; kc < Kpad; kc += 32) {
        bf16x8 afr[2];
        const int k8 = kc + kb8;
        #pragma unroll
        for (int i = 0; i < 2; ++i) {
            const int r = rowBase + i * 16 + l16;
            bf16x8 v = {0, 0, 0, 0, 0, 0, 0, 0};
            if (k8 < K1) {
                if (X1) v = *(const bf16x8*)(X1 + (size_t)(r & 1023) * K1 + k8);
            } else if (k8 < K1 + K2) {
                v = *(const bf16x8*)(X2 + (size_t)r * K2 + (k8 - K1));
            }
            afr[i] = v;
        }
        #pragma unroll
        for (int g = 0; g < 3; ++g)
            #pragma unroll
            for (int j = 0; j < 2; ++j) {
                const bf16x8 b = *(const bf16x8*)(Wih + (size_t)(g * G + colBase + j * 16 + l16) * Kpad + k8);
                gi[g][0][j] = __builtin_amdgcn_mfma_f32_16x16x32_bf16(afr[0], b, gi[g][0][j], 0, 0, 0);
                gi[g][1][j] = __builtin_amdgcn_mfma_f32_16x16x32_bf16(afr[1], b, gi[g][1][j], 0, 0, 0);
            }
    }
    for (int kc = 0; kc < G; kc += 32) {
        const int k8 = kc + kb8;
        bf16x8 afr[2];
        #pragma unroll
        for (int i = 0; i < 2; ++i)
            afr[i] = *(const bf16x8*)(Hb + (size_t)(rowBase + i * 16 + l16) * G + k8);
        #pragma unroll
        for (int g = 0; g < 3; ++g)
            #pragma unroll
            for (int j = 0; j < 2; ++j) {
                const bf16x8 b = *(const bf16x8*)(Whh + (size_t)(g * G + colBase + j * 16 + l16) * G + k8);
                gh[g][0][j] = __builtin_amdgcn_mfma_f32_16x16x32_bf16(afr[0], b, gh[g][0][j], 0, 0, 0);
                gh[g][1][j] = __builtin_amdgcn_mfma_f32_16x16x32_bf16(afr[1], b, gh[g][1][j], 0, 0, 0);
            }
    }

    const int r4 = (lane >> 4) * 4;
    #pragma unroll
    for (int j = 0; j < 2; ++j) {
        const int col = colBase + j * 16 + l16;
        const float bi0 = bih[col],         bh0 = bhh[col];
        const float bi1 = bih[G + col],     bh1 = bhh[G + col];
        const float bi2 = bih[2 * G + col], bh2 = bhh[2 * G + col];
        #pragma unroll
        for (int i = 0; i < 2; ++i) {
            #pragma unroll
            for (int q = 0; q < 4; ++q) {
                const int row = rowBase + i * 16 + r4 + q;
                const float rr = sigmoidf_(gi[0][i][j][q] + bi0 + gh[0][i][j][q] + bh0);
                const float zz = sigmoidf_(gi[1][i][j][q] + bi1 + gh[1][i][j][q] + bh1);
                const float nn = tanhf(gi[2][i][j][q] + bi2 + rr * (gh[2][i][j][q] + bh2));
                const float hp = Hprev[(size_t)row * G + col];
                const float hv = (1.f - zz) * nn + zz * hp;
                Hnew[(size_t)row * G + col] = hv;
                Hnewb[(size_t)row * G + col] = (short)f2bf(hv);
            }
        }
    }
}

__device__ __forceinline__ void gemm_tile(
    const short* __restrict__ Xb, const short* __restrict__ Wb,
    const float* __restrict__ bias, float* __restrict__ Out,
    int Ncols, int K, int rowBase, int colBase, int lane)
{
    const int l16 = lane & 15;
    const int kb8 = (lane >> 4) * 8;
    const f32x4 z4 = {0.f, 0.f, 0.f, 0.f};
    f32x4 acc[2][2] = {{z4, z4}, {z4, z4}};

    for (int kc = 0; kc < K; kc += 32) {
        const int k8 = kc + kb8;
        const bf16x8 a0 = *(const bf16x8*)(Xb + (size_t)(rowBase + l16) * K + k8);
        const bf16x8 a1 = *(const bf16x8*)(Xb + (size_t)(rowBase + 16 + l16) * K + k8);
        const bf16x8 b0 = *(const bf16x8*)(Wb + (size_t)(colBase + l16) * K + k8);
        const bf16x8 b1 = *(const bf16x8*)(Wb + (size_t)(colBase + 16 + l16) * K + k8);
        acc[0][0] = __builtin_amdgcn_mfma_f32_16x16x32_bf16(a0, b0, acc[0][0], 0, 0, 0);
        acc[0][1] = __builtin_amdgcn_mfma_f32_16x16x32_bf16(a0, b1, acc[0][1], 0, 0, 0);
        acc[1][0] = __builtin_amdgcn_mfma_f32_16x16x32_bf16(a1, b0, acc[1][0], 0, 0, 0);
        acc[1][1] = __builtin_amdgcn_mfma_f32_16x16x32_bf16(a1, b1, acc[1][1], 0, 0, 0);
    }
    const int r4 = (lane >> 4) * 4;
    #pragma unroll
    for (int j = 0; j < 2; ++j) {
        const int col = colBase + j * 16 + l16;
        if (col >= Ncols) continue;
        const float bv = bias[col];
        #pragma unroll
        for (int i = 0; i < 2; ++i)
            #pragma unroll
            for (int q = 0; q < 4; ++q) {
                const int row = rowBase + i * 16 + r4 + q;
                Out[(size_t)row * Ncols + col] = acc[i][j][q] + bv;
            }
    }
}

// ---------------------------------------------------------------------------
// phaseA: enc-GRU(t) | rel-GRU(t) | deferred dec-GRU(t-1)  (round-7, proven)
// ---------------------------------------------------------------------------
__global__ __launch_bounds__(256) void phaseA(
    const short* __restrict__ ep, const short* __restrict__ er,
    const short* __restrict__ enc_wih, const float* __restrict__ enc_bih,
    const short* __restrict__ enc_whh, const float* __restrict__ enc_bhh,
    const short* __restrict__ rel_wih, const float* __restrict__ rel_bih,
    const short* __restrict__ rel_whh, const float* __restrict__ rel_bhh,
    const short* __restrict__ dec_wih, const float* __restrict__ dec_bih,
    const short* __restrict__ dec_whh, const float* __restrict__ dec_bhh,
    const float* __restrict__ hc, const short* __restrict__ hbc,
    float* __restrict__ hn, short* __restrict__ hbn,
    const float* __restrict__ hrc, const short* __restrict__ hrbc,
    float* __restrict__ hrn, short* __restrict__ hrbn,
    const float* __restrict__ hfc, const short* __restrict__ hfbc,
    float* __restrict__ hfn, short* __restrict__ hfbn,
    const short* __restrict__ reads_b,
    int encBlocks, int relBlocks)
{
    const int bid = blockIdx.x;
    const int wave = threadIdx.x >> 6;
    const int lane = threadIdx.x & 63;

    if (bid < encBlocks) {
        const int tile = bid * 4 + wave;
        gru_tile(ep, 16, reads_b, 128, enc_wih, 160, enc_bih,
                 hbc, enc_whh, enc_bhh, hc, hn, hbn, C_,
                 (tile >> 3) * 32, (tile & 7) * 32, lane);
    } else if (bid < encBlocks + relBlocks) {
        const int tile = (bid - encBlocks) * 4 + wave;
        gru_tile(er, 16, nullptr, 0, rel_wih, 32, rel_bih,
                 hrbc, rel_whh, rel_bhh, hrc, hrn, hrbn, C_,
                 (tile >> 3) * 32, (tile & 7) * 32, lane);
    } else {
        const int tile = (bid - encBlocks - relBlocks) * 4 + wave;
        gru_tile(hbc, 256, reads_b, 128, dec_wih, 384, dec_bih,
                 hfbc, dec_whh, dec_bhh, hfc, hfn, hfbn, D_,
                 (tile / 12) * 32, (tile % 12) * 32, lane);
    }
}

// ---------------------------------------------------------------------------
// phaseHeads: wp GEMM (416 tiles) | rp GEMM (672 tiles) | out(t-1) rows.
// All MFMA; weights zero-padded to 416/672 rows.
// ---------------------------------------------------------------------------
__global__ __launch_bounds__(256) void phaseHeads(
    const short* __restrict__ hbn, const short* __restrict__ write_w_b,
    const float* __restrict__ write_b, float* __restrict__ wp,
    const short* __restrict__ hrbn, const short* __restrict__ read_w_b,
    const float* __restrict__ read_b, float* __restrict__ rp,
    const float* __restrict__ hfn, const float* __restrict__ out_w,
    const float* __restrict__ out_b, float* __restrict__ predrel,
    int outT, int wpBlocks, int rpBlocks)
{
    const int bid = blockIdx.x;
    const int wave = threadIdx.x >> 6;
    const int lane = threadIdx.x & 63;

    if (bid < wpBlocks) {
        const int tile = bid * 4 + wave;                 // 416: 32 row-tiles x 13 col-tiles
        gemm_tile(hbn, write_w_b, write_b, wp, 385, C_,
                  (tile & 31) * 32, (tile >> 5) * 32, lane);
    } else if (bid < wpBlocks + rpBlocks) {
        const int tile = (bid - wpBlocks) * 4 + wave;    // 672: 32 row-tiles x 21 col-tiles
        gemm_tile(hrbn, read_w_b, read_b, rp, 645, C_,
                  (tile & 31) * 32, (tile >> 5) * 32, lane);
    } else {
        // out(t-1): 8-lane groups, 8 rows per wave
        const int widx = (bid - wpBlocks - rpBlocks) * 4 + wave;
        const int g = lane >> 3, li = lane & 7;
        const int row = widx * 8 + g;                    // < 5120
        const float* hrow = hfn + (size_t)row * D_;
        float a0 = 0.f, a1 = 0.f;
        for (int k = li; k < D_; k += 8) {
            const float v = hrow[k];
            a0 += v * out_w[k];
            a1 += v * out_w[D_ + k];
        }
        a0 += __shfl_xor(a0, 1); a0 += __shfl_xor(a0, 2); a0 += __shfl_xor(a0, 4);
        a1 += __shfl_xor(a1, 1); a1 += __shfl_xor(a1, 2); a1 += __shfl_xor(a1, 4);
        if (li == 0) {
            const int hh = row >> 10, aa = row & 1023;
            float* o = predrel + (((size_t)aa * H_ + hh) * TFUT_ + outT) * 2;
            o[0] = a0 + out_b[0];
            o[1] = a1 + out_b[1];
        }
    }
}

// ---------------------------------------------------------------------------
// NTM write (round-5 verbatim) + bf16 hi/lo split of updated slots.
// ---------------------------------------------------------------------------
__global__ __launch_bounds__(256) void write_mem_k(const float* __restrict__ wp,
                                                   float* __restrict__ mem,
                                                   short* __restrict__ memhi, short* __restrict__ memlo,
                                                   float* __restrict__ normsG)
{
    const int a = blockIdx.x;
    const int b = a >> 4, p = a & 15;
    __shared__ float kw[128], er[128], ad[128], red[256], ww[16], logit[16];
    __shared__ float buf[2048];
    __shared__ float beta_s, knorm_s;
    const int tid = threadIdx.x;
    const float* w = wp + (size_t)a * 385;
    if (tid < 128) {
        kw[tid] = tanhf(w[tid]);
        er[tid] = sigmoidf_(w[129 + tid]);
        ad[tid] = tanhf(w[257 + tid]);
    }
    if (tid == 0) beta_s = softplusf_(w[128]);
    __syncthreads();

    red[tid] = (tid < 128) ? kw[tid] * kw[tid] : 0.f;
    __syncthreads();
    for (int s = 128; s > 0; s >>= 1) { if (tid < s) red[tid] += red[tid + s]; __syncthreads(); }
    if (tid == 0) knorm_s = sqrtf(red[0]) + 1e-16f;
    __syncthreads();

    const int s = tid >> 4, j = tid & 15;
    float dot = 0.f, ss = 0.f;
    {
        const float* mrow = mem + ((size_t)(b * N_) + p * 16 + s) * M_;
        for (int k = j; k < 128; k += 16) { float v = mrow[k]; dot += kw[k] * v; ss += v * v; }
    }
    red[tid] = dot; __syncthreads();
    for (int st = 8; st > 0; st >>= 1) { if (j < st) red[tid] += red[tid + st]; __syncthreads(); }
    float dotf = red[s * 16];
    __syncthreads();
    red[tid] = ss; __syncthreads();
    for (int st = 8; st > 0; st >>= 1) { if (j < st) red[tid] += red[tid + st]; __syncthreads(); }
    float ssf = red[s * 16];
    if (j == 0) {
        float mn = sqrtf(ssf) + 1e-16f;
        logit[s] = beta_s * (dotf / (mn * knorm_s));
    }
    __syncthreads();
    if (tid == 0) {
        float mx = -1e30f;
        for (int i = 0; i < 16; ++i) mx = fmaxf(mx, logit[i]);
        float sum = 0.f;
        for (int i = 0; i < 16; ++i) { float e = __expf(logit[i] - mx); ww[i] = e; sum += e; }
        float inv = 1.f / sum;
        for (int i = 0; i < 16; ++i) ww[i] *= inv;
    }
    __syncthreads();
    for (int idx = tid; idx < 16 * 128; idx += 256) {
        int si = idx >> 7, m = idx & 127;
        size_t g = ((size_t)(b * N_) + p * 16 + si) * M_ + m;
        float wwv = ww[si];
        float v = mem[g] * (1.f - wwv * er[m]) + wwv * ad[m];
        mem[g] = v;
        const short hv = (short)f2bf(v);
        memhi[g] = hv;
        memlo[g] = (short)f2bf(v - bf2f(hv));
        buf[idx] = v;
    }
    __syncthreads();
    {
        float ssq = 0.f;
        #pragma unroll
        for (int i = 0; i < 8; ++i) { float v = buf[s * 128 + j + 16 * i]; ssq += v * v; }
        #pragma unroll
        for (int m = 1; m < 16; m <<= 1) ssq += __shfl_xor(ssq, m);
        if (j == 0) normsG[b * N_ + p * 16 + s] = sqrtf(ssq) + 1e-16f;
    }
}

// ---------------------------------------------------------------------------
// NTM read (round-5 verbatim; sims B-fragments from precomputed hi/lo bf16)
// ---------------------------------------------------------------------------
__global__ __launch_bounds__(256) void read_k2(const float* __restrict__ rp,
                                               const float* __restrict__ mem,
                                               const short* __restrict__ memhi,
                                               const short* __restrict__ memlo,
                                               const float* __restrict__ normsG,
                                               short* __restrict__ reads_b)
{
    const int b = blockIdx.x;
    const int h = blockIdx.y;
    __shared__ __align__(16) float kq[16 * 132];
    __shared__ float S[16 * 260];
    __shared__ float beta_s[16], knorm_s[16], inv_s[16];
    const int t = threadIdx.x;
    const int a = t >> 4;
    const int sub = t & 15;

    // P0: kq = tanh(kr) (fp32 LDS), per-agent knorm & beta
    {
        const float* base = rp + ((size_t)(b * 16 + a)) * 645 + h * 129;
        const int k0 = sub * 8;
        float v[8]; float ss = 0.f;
        #pragma unroll
        for (int r = 0; r < 8; ++r) { v[r] = tanhf(base[k0 + r]); ss += v[r] * v[r]; }
        float* dst = kq + a * 132 + k0;
        *(float4*)dst = make_float4(v[0], v[1], v[2], v[3]);
        *(float4*)(dst + 4) = make_float4(v[4], v[5], v[6], v[7]);
        #pragma unroll
        for (int m = 1; m < 16; m <<= 1) ss += __shfl_xor(ss, m);
        if (sub == 0) {
            knorm_s[a] = sqrtf(ss) + 1e-16f;
            beta_s[a] = softplusf_(base[128]);
        }
    }
    __syncthreads();

    // P1: sims via hi/lo MFMA (B operands precomputed in memhi/memlo)
    {
        const int wave = t >> 6, lane = t & 63;
        const int l16 = lane & 15, kb8 = (lane >> 4) * 8;
        const int slotBase = wave * 64;
        const f32x4 z4 = {0.f, 0.f, 0.f, 0.f};
        f32x4 acc[4] = {z4, z4, z4, z4};
        const short* mbh = memhi + (size_t)b * N_ * M_;
        const short* mbl = memlo + (size_t)b * N_ * M_;
        #pragma unroll
        for (int kc = 0; kc < 128; kc += 32) {
            const float* ap = kq + l16 * 132 + kc + kb8;
            bf16x8 ah, al;
            #pragma unroll
            for (int r = 0; r < 8; ++r) {
                const float av = ap[r];
                const short hv = (short)f2bf(av);
                ah[r] = hv; al[r] = (short)f2bf(av - bf2f(hv));
            }
            #pragma unroll
            for (int tt = 0; tt < 4; ++tt) {
                const size_t roff = (size_t)(slotBase + tt * 16 + l16) * M_ + kc + kb8;
                const bf16x8 bh = *(const bf16x8*)(mbh + roff);
                const bf16x8 bl = *(const bf16x8*)(mbl + roff);
                acc[tt] = __builtin_amdgcn_mfma_f32_16x16x32_bf16(ah, bh, acc[tt], 0, 0, 0);
                acc[tt] = __builtin_amdgcn_mfma_f32_16x16x32_bf16(ah, bl, acc[tt], 0, 0, 0);
                acc[tt] = __builtin_amdgcn_mfma_f32_16x16x32_bf16(al, bh, acc[tt], 0, 0, 0);
            }
        }
        const int r4 = (lane >> 4) * 4;
        #pragma unroll
        for (int tt = 0; tt < 4; ++tt) {
            const int slot = slotBase + tt * 16 + l16;
            const float nv = normsG[b * N_ + slot];
            #pragma unroll
            for (int q = 0; q < 4; ++q) {
                const int aq = r4 + q;
                const float lg = ((slot >> 4) == aq) ? -1e30f
                               : beta_s[aq] * acc[tt][q] / (nv * knorm_s[aq]);
                S[aq * 260 + slot] = lg;
            }
        }
    }
    __syncthreads();

    // P2: per-agent softmax over 256 slots
    {
        float mx = -1e30f;
        #pragma unroll
        for (int i = 0; i < 16; ++i) mx = fmaxf(mx, S[a * 260 + sub + 16 * i]);
        #pragma unroll
        for (int m = 1; m < 16; m <<= 1) mx = fmaxf(mx, __shfl_xor(mx, m));
        float e[16]; float sum = 0.f;
        #pragma unroll
        for (int i = 0; i < 16; ++i) { e[i] = __expf(S[a * 260 + sub + 16 * i] - mx); sum += e[i]; }
        #pragma unroll
        for (int i = 0; i < 16; ++i) S[a * 260 + sub + 16 * i] = e[i];
        #pragma unroll
        for (int m = 1; m < 16; m <<= 1) sum += __shfl_xor(sum, m);
        if (sub == 0) inv_s[a] = 1.f / sum;
    }
    __syncthreads();

    // P3: PV fp32
    {
        const int m0 = sub * 8;
        const float* mb = mem + (size_t)b * N_ * M_ + m0;
        float acc[8];
        #pragma unroll
        for (int r = 0; r < 8; ++r) acc[r] = 0.f;
        const float* Sa = S + a * 260;
        #pragma unroll 4
        for (int n = 0; n < N_; ++n) {
            const float w = Sa[n];
            const float4 v0 = *(const float4*)(mb + (size_t)n * M_);
            const float4 v1 = *(const float4*)(mb + (size_t)n * M_ + 4);
            acc[0] = fmaf(w, v0.x, acc[0]); acc[1] = fmaf(w, v0.y, acc[1]);
            acc[2] = fmaf(w, v0.z, acc[2]); acc[3] = fmaf(w, v0.w, acc[3]);
            acc[4] = fmaf(w, v1.x, acc[4]); acc[5] = fmaf(w, v1.y, acc[5]);
            acc[6] = fmaf(w, v1.z, acc[6]); acc[7] = fmaf(w, v1.w, acc[7]);
        }
        const float inv = inv_s[a];
        short pk[8];
        #pragma unroll
        for (int r = 0; r < 8; ++r) pk[r] = (short)f2bf(acc[r] * inv);
        *(bf16x8*)(reads_b + ((size_t)h * A_ + b * 16 + a) * M_ + m0) = *(bf16x8*)pk;
    }
}

__global__ __launch_bounds__(256) void cumsum_k(const float* __restrict__ past,
                                                const float* __restrict__ predrel,
                                                float* __restrict__ pred)
{
    const int idx = blockIdx.x * 256 + threadIdx.x;
    if (idx >= A_ * H_ * 2) return;
    const int c = idx & 1;
    const int ah = idx >> 1;
    const int a = ah / H_;
    float acc = past[((size_t)a * TPAST_ + TPAST_ - 1) * 2 + c];
    const float* pr = predrel + (size_t)ah * TFUT_ * 2 + c;
    float* pd = pred + (size_t)ah * TFUT_ * 2 + c;
    for (int t = 0; t < TFUT_; ++t) { acc += pr[t * 2]; pd[t * 2] = acc; }
}

extern "C" void kernel_launch(void* const* d_in, const int* in_sizes, int n_in,
                              void* d_out, int out_size, void* d_ws, size_t ws_size,
                              hipStream_t stream)
{
    const float* past       = (const float*)d_in[0];
    const float* past_rel   = (const float*)d_in[1];
    const float* ep_w1      = (const float*)d_in[2];
    const float* ep_b1      = (const float*)d_in[3];
    const float* ep_w2      = (const float*)d_in[4];
    const float* ep_b2      = (const float*)d_in[5];
    const float* er_w1      = (const float*)d_in[6];
    const float* er_b1      = (const float*)d_in[7];
    const float* er_w2      = (const float*)d_in[8];
    const float* er_b2      = (const float*)d_in[9];
    const float* enc_wih    = (const float*)d_in[10];
    const float* enc_whh    = (const float*)d_in[11];
    const float* enc_bih    = (const float*)d_in[12];
    const float* enc_bhh    = (const float*)d_in[13];
    const float* rel_wih    = (const float*)d_in[14];
    const float* rel_whh    = (const float*)d_in[15];
    const float* rel_bih    = (const float*)d_in[16];
    const float* rel_bhh    = (const float*)d_in[17];
    const float* dec_wih    = (const float*)d_in[18];
    const float* dec_whh    = (const float*)d_in[19];
    const float* dec_bih    = (const float*)d_in[20];
    const float* dec_bhh    = (const float*)d_in[21];
    const float* out_w      = (const float*)d_in[22];
    const float* out_b      = (const float*)d_in[23];
    const float* read_w     = (const float*)d_in[24];
    const float* read_b     = (const float*)d_in[25];
    const float* write_w    = (const float*)d_in[26];
    const float* write_b    = (const float*)d_in[27];
    const float* init_r     = (const float*)d_in[28];
    const float* h_bias     = (const float*)d_in[29];
    const float* h_rel_bias = (const float*)d_in[30];
    const float* h_fut_bias = (const float*)d_in[31];
    const float* mem_bias   = (const float*)d_in[32];

    float* pred    = (float*)d_out;
    float* predrel = pred + (size_t)A_ * H_ * TFUT_ * 2;

    float* ws = (float*)d_ws;
    size_t off = 0;
    auto alloc = [&](size_t n) { float* p = ws + off; off += n; return p; };
    float* h0     = alloc((size_t)A_ * C_);
    float* h1     = alloc((size_t)A_ * C_);
    float* hr0    = alloc((size_t)A_ * C_);
    float* hr1    = alloc((size_t)A_ * C_);
    float* hf0    = alloc((size_t)H_ * A_ * D_);
    float* hf1    = alloc((size_t)H_ * A_ * D_);
    float* mem    = alloc((size_t)B_ * N_ * M_);
    float* wp     = alloc((size_t)A_ * 385);
    float* rp     = alloc((size_t)A_ * 645);
    float* normsG = alloc((size_t)B_ * N_);

    short* sws = (short*)(ws + off);
    size_t soff = 0;
    auto salloc = [&](size_t n) { short* p = sws + soff; soff += n; return p; };
    short* emb_p_b   = salloc((size_t)TPAST_ * A_ * EMB_);
    short* emb_r_b   = salloc((size_t)TPAST_ * A_ * EMB_);
    short* hb0       = salloc((size_t)A_ * C_);
    short* hb1       = salloc((size_t)A_ * C_);
    short* hrb0      = salloc((size_t)A_ * C_);
    short* hrb1      = salloc((size_t)A_ * C_);
    short* hfb0      = salloc((size_t)H_ * A_ * D_);
    short* hfb1      = salloc((size_t)H_ * A_ * D_);
    short* reads_b   = salloc((size_t)H_ * A_ * M_);
    short* memhi     = salloc((size_t)B_ * N_ * M_);
    short* memlo     = salloc((size_t)B_ * N_ * M_);
    short* enc_wih_b = salloc((size_t)768 * 160);
    short* enc_whh_b = salloc((size_t)768 * 256);
    short* rel_wih_b = salloc((size_t)768 * 32);
    short* rel_whh_b = salloc((size_t)768 * 256);
    short* dec_wih_b = salloc((size_t)1152 * 384);
    short* dec_whh_b = salloc((size_t)1152 * 384);
    short* write_w_b = salloc((size_t)416 * 256);
    short* read_w_b  = salloc((size_t)672 * 256);
    (void)ws_size; (void)in_sizes; (void)n_in; (void)out_size;

    // prologue (3 dispatches)
    Cvt8 cp;
    cp.c[0] = {enc_wih, enc_wih_b, 768, 144, 160, 768 * 160};
    cp.c[1] = {enc_whh, enc_whh_b, 768, 256, 256, 768 * 256};
    cp.c[2] = {rel_wih, rel_wih_b, 768, 16, 32, 768 * 32};
    cp.c[3] = {rel_whh, rel_whh_b, 768, 256, 256, 768 * 256};
    cp.c[4] = {dec_wih, dec_wih_b, 1152, 384, 384, 1152 * 384};
    cp.c[5] = {dec_whh, dec_whh_b, 1152, 384, 384, 1152 * 384};
    cp.c[6] = {write_w, write_w_b, 385, 256, 256, 416 * 256};
    cp.c[7] = {read_w, read_w_b, 645, 256, 256, 672 * 256};
    convert_all<<<1024, 256, 0, stream>>>(cp);

    init_k<<<(B_ * N_ * M_ + 255) / 256, 256, 0, stream>>>(
        h0, h_bias, hb0, hr0, h_rel_bias, hrb0, hf0, h_fut_bias, hfb0,
        reads_b, init_r, mem, memhi, memlo, normsG, mem_bias);
    embed2_k<<<(2 * A_ * TPAST_ + 255) / 256, 256, 0, stream>>>(
        past, past_rel, ep_w1, ep_b1, ep_w2, ep_b2, er_w1, er_b1, er_w2, er_b2,
        emb_p_b, emb_r_b);

    float *hc = h0, *hn = h1, *hrc = hr0, *hrn = hr1, *hfc = hf0, *hfn = hf1;
    short *hbc = hb0, *hbn = hb1, *hrbc = hrb0, *hrbn = hrb1, *hfbc = hfb0, *hfbn = hfb1;

    const dim3 g_read(B_, H_);   // (64, 5)

    for (int t = 0; t < TTOT_; ++t) {
        const short* ep = (t < TPAST_) ? emb_p_b + (size_t)t * A_ * EMB_ : nullptr;
        const short* er = (t < TPAST_) ? emb_r_b + (size_t)t * A_ * EMB_ : nullptr;

        // phase A: enc(t) + rel(t) + dec(t-1)  [dec only when t>=1]
        const int gridA = (t == 0) ? 128 : 608;
        phaseA<<<gridA, 256, 0, stream>>>(
            ep, er,
            enc_wih_b, enc_bih, enc_whh_b, enc_bhh,
            rel_wih_b, rel_bih, rel_whh_b, rel_bhh,
            dec_wih_b, dec_bih, dec_whh_b, dec_bhh,
            hc, hbc, hn, hbn,
            hrc, hrbc, hrn, hrbn,
            hfc, hfbc, hfn, hfbn,
            reads_b, 64, 64);

        // phase Heads: wp GEMM + rp GEMM (+ out(t-1) when t>=21)
        const int gridH = (t >= 21) ? 432 : 272;
        phaseHeads<<<gridH, 256, 0, stream>>>(
            hbn, write_w_b, write_b, wp,
            hrbn, read_w_b, read_b, rp,
            hfn, out_w, out_b, predrel, t - 21, 104, 168);

        // memory write
        write_mem_k<<<A_, 256, 0, stream>>>(wp, mem, memhi, memlo, normsG);

        // memory read -> reads_b(t)
        read_k2<<<g_read, 256, 0, stream>>>(rp, mem, memhi, memlo, normsG, reads_b);

        // swaps
        float* tf; short* ts;
        tf = hc; hc = hn; hn = tf;       ts = hbc; hbc = hbn; hbn = ts;
        tf = hrc; hrc = hrn; hrn = tf;   ts = hrbc; hrbc = hrbn; hrbn = ts;
        if (t >= 1) {
            tf = hfc; hfc = hfn; hfn = tf;  ts = hfbc; hfbc = hfbn; hfbn = ts;
        }
    }

    // epilogue: dec(49), out(49), cumsum
    phaseA<<<480, 256, 0, stream>>>(
        nullptr, nullptr,
        enc_wih_b, enc_bih, enc_whh_b, enc_bhh,
        rel_wih_b, rel_bih, rel_whh_b, rel_bhh,
        dec_wih_b, dec_bih, dec_whh_b, dec_bhh,
        hc, hbc, hn, hbn,
        hrc, hrbc, hrn, hrbn,
        hfc, hfbc, hfn, hfbn,
        reads_b, 0, 0);
    phaseHeads<<<160, 256, 0, stream>>>(
        hbn, write_w_b, write_b, wp,
        hrbn, read_w_b, read_b, rp,
        hfn, out_w, out_b, predrel, TFUT_ - 1, 0, 0);
    cumsum_k<<<(A_ * H_ * 2 + 255) / 256, 256, 0, stream>>>(past, predrel, pred);
}

// Round 9
// 6177.915 us; speedup vs baseline: 4.3637x; 1.1687x over previous
//
#include <hip/hip_runtime.h>
#include <math.h>

#define B_    64
#define APER_ 16
#define A_    1024
#define TPAST_ 20
#define TFUT_  30
#define C_    256
#define M_    128
#define N_    256
#define H_    5
#define EMB_  16
#define D_    384
#define TTOT_ 50

typedef short bf16x8 __attribute__((ext_vector_type(8)));
typedef float f32x4 __attribute__((ext_vector_type(4)));

__device__ __forceinline__ float sigmoidf_(float x) { return 1.0f / (1.0f + expf(-x)); }
__device__ __forceinline__ float softplusf_(float x) { return (x > 20.0f) ? x : log1pf(expf(x)); }
__device__ __forceinline__ unsigned short f2bf(float f) {
    unsigned u = __float_as_uint(f);
    return (unsigned short)((u + 0x7FFFu + ((u >> 16) & 1u)) >> 16);
}
__device__ __forceinline__ float bf2f(short s) {
    return __uint_as_float(((unsigned)(unsigned short)s) << 16);
}

// ---------------------------------------------------------------------------
// Prologue: all 8 weight conversions in ONE dispatch (grid-strided segments)
// ---------------------------------------------------------------------------
struct Cvt { const float* src; short* dst; int rows, sk, dk, total; };
struct Cvt8 { Cvt c[8]; };

__global__ __launch_bounds__(256) void convert_all(Cvt8 p)
{
    const int stride = gridDim.x * 256;
    #pragma unroll
    for (int s = 0; s < 8; ++s) {
        const Cvt d = p.c[s];
        for (int idx = blockIdx.x * 256 + threadIdx.x; idx < d.total; idx += stride) {
            const int r = idx / d.dk, k = idx % d.dk;
            float v = (k < d.sk && r < d.rows) ? d.src[(size_t)r * d.sk + k] : 0.f;
            d.dst[idx] = (short)f2bf(v);
        }
    }
}

__global__ __launch_bounds__(256) void embed2_k(const float* __restrict__ past, const float* __restrict__ past_rel,
                                                const float* __restrict__ pw1, const float* __restrict__ pb1,
                                                const float* __restrict__ pw2, const float* __restrict__ pb2,
                                                const float* __restrict__ rw1, const float* __restrict__ rb1,
                                                const float* __restrict__ rw2, const float* __restrict__ rb2,
                                                short* __restrict__ emb_p, short* __restrict__ emb_r)
{
    const int idx0 = blockIdx.x * 256 + threadIdx.x;
    const int half = A_ * TPAST_;
    if (idx0 >= 2 * half) return;
    const bool second = idx0 >= half;
    const int idx = second ? idx0 - half : idx0;
    const float* x = second ? past_rel : past;
    const float* w1 = second ? rw1 : pw1; const float* b1 = second ? rb1 : pb1;
    const float* w2 = second ? rw2 : pw2; const float* b2 = second ? rb2 : pb2;
    short* emb = second ? emb_r : emb_p;

    const int a = idx / TPAST_, t = idx % TPAST_;
    const float x0 = x[(size_t)idx * 2], x1 = x[(size_t)idx * 2 + 1];
    float hbuf[8];
    #pragma unroll
    for (int j = 0; j < 8; ++j) hbuf[j] = fmaxf(0.f, w1[j * 2] * x0 + w1[j * 2 + 1] * x1 + b1[j]);
    short* e = emb + ((size_t)t * A_ + a) * EMB_;
    #pragma unroll
    for (int i = 0; i < 16; ++i) {
        float acc = b2[i];
        #pragma unroll
        for (int j = 0; j < 8; ++j) acc += w2[i * 8 + j] * hbuf[j];
        e[i] = (short)f2bf(acc);
    }
}

__global__ __launch_bounds__(256) void init_k(float* __restrict__ h, const float* __restrict__ h_bias, short* __restrict__ hb,
                                              float* __restrict__ hr, const float* __restrict__ hr_bias, short* __restrict__ hrb,
                                              float* __restrict__ hf, const float* __restrict__ hf_bias, short* __restrict__ hfb,
                                              short* __restrict__ reads_b, const float* __restrict__ init_r,
                                              float* __restrict__ mem, short* __restrict__ memhi, short* __restrict__ memlo,
                                              float* __restrict__ normsG, const float* __restrict__ mem_bias)
{
    const int idx = blockIdx.x * 256 + threadIdx.x;
    if (idx < B_ * N_ * M_) {
        const float v = mem_bias[idx & (N_ * M_ - 1)];
        mem[idx] = v;
        const short hv = (short)f2bf(v);
        memhi[idx] = hv;
        memlo[idx] = (short)f2bf(v - bf2f(hv));
    }
    if (idx < B_ * N_) {
        const float* r = mem_bias + (size_t)(idx & (N_ - 1)) * M_;
        float ss = 0.f;
        for (int k = 0; k < M_; ++k) ss += r[k] * r[k];
        normsG[idx] = sqrtf(ss) + 1e-16f;
    }
    if (idx < A_ * C_) {
        float v = h_bias[idx & (C_ - 1)];
        h[idx] = v; hb[idx] = (short)f2bf(v);
        v = hr_bias[idx & (C_ - 1)];
        hr[idx] = v; hrb[idx] = (short)f2bf(v);
    }
    if (idx < H_ * A_ * D_) {
        float v = hf_bias[idx % D_];
        hf[idx] = v; hfb[idx] = (short)f2bf(v);
    }
    if (idx < A_ * M_) reads_b[idx] = (short)f2bf(init_r[idx & (M_ - 1)]);
}

// ---------------------------------------------------------------------------
// GRU tile v2: shared r/z accumulators (gi+gh fused into one MFMA acc chain),
// single fused k-loop interleaving Wih and Whh streams for ILP.
// Accumulators: 16 f32x4 (was 24) -> lower VGPR, higher occupancy.
// ---------------------------------------------------------------------------
__device__ __forceinline__ void gru_tile(
    const short* __restrict__ X1, int K1,
    const short* __restrict__ X2, int K2,
    const short* __restrict__ Wih, int Kpad,
    const float* __restrict__ bih,
    const short* __restrict__ Hb, const short* __restrict__ Whh,
    const float* __restrict__ bhh,
    const float* __restrict__ Hprev,
    float* __restrict__ Hnew, short* __restrict__ Hnewb,
    int G, int rowBase, int colBase, int lane)
{
    const int l16 = lane & 15;
    const int kb8 = (lane >> 4) * 8;
    const f32x4 z4 = {0.f, 0.f, 0.f, 0.f};
    f32x4 ar[2][2], az[2][2], ani[2][2], anh[2][2];
    #pragma unroll
    for (int i = 0; i < 2; ++i)
        #pragma unroll
        for (int j = 0; j < 2; ++j) { ar[i][j] = z4; az[i][j] = z4; ani[i][j] = z4; anh[i][j] = z4; }

    const int kmax = (Kpad > G) ? Kpad : G;
    for (int kc = 0; kc < kmax; kc += 32) {
        const int k8 = kc + kb8;
        if (kc < Kpad) {
            bf16x8 ax[2];
            #pragma unroll
            for (int i = 0; i < 2; ++i) {
                const int r = rowBase + i * 16 + l16;
                bf16x8 v = {0, 0, 0, 0, 0, 0, 0, 0};
                if (k8 < K1) {
                    if (X1) v = *(const bf16x8*)(X1 + (size_t)(r & 1023) * K1 + k8);
                } else if (k8 < K1 + K2) {
                    v = *(const bf16x8*)(X2 + (size_t)r * K2 + (k8 - K1));
                }
                ax[i] = v;
            }
            #pragma unroll
            for (int j = 0; j < 2; ++j) {
                const size_t wb = (size_t)(colBase + j * 16 + l16) * Kpad + k8;
                const bf16x8 b0 = *(const bf16x8*)(Wih + wb);
                const bf16x8 b1 = *(const bf16x8*)(Wih + (size_t)G * Kpad + wb);
                const bf16x8 b2 = *(const bf16x8*)(Wih + (size_t)2 * G * Kpad + wb);
                ar[0][j]  = __builtin_amdgcn_mfma_f32_16x16x32_bf16(ax[0], b0, ar[0][j], 0, 0, 0);
                ar[1][j]  = __builtin_amdgcn_mfma_f32_16x16x32_bf16(ax[1], b0, ar[1][j], 0, 0, 0);
                az[0][j]  = __builtin_amdgcn_mfma_f32_16x16x32_bf16(ax[0], b1, az[0][j], 0, 0, 0);
                az[1][j]  = __builtin_amdgcn_mfma_f32_16x16x32_bf16(ax[1], b1, az[1][j], 0, 0, 0);
                ani[0][j] = __builtin_amdgcn_mfma_f32_16x16x32_bf16(ax[0], b2, ani[0][j], 0, 0, 0);
                ani[1][j] = __builtin_amdgcn_mfma_f32_16x16x32_bf16(ax[1], b2, ani[1][j], 0, 0, 0);
            }
        }
        if (kc < G) {
            bf16x8 ah[2];
            #pragma unroll
            for (int i = 0; i < 2; ++i)
                ah[i] = *(const bf16x8*)(Hb + (size_t)(rowBase + i * 16 + l16) * G + k8);
            #pragma unroll
            for (int j = 0; j < 2; ++j) {
                const size_t wb = (size_t)(colBase + j * 16 + l16) * G + k8;
                const bf16x8 b0 = *(const bf16x8*)(Whh + wb);
                const bf16x8 b1 = *(const bf16x8*)(Whh + (size_t)G * G + wb);
                const bf16x8 b2 = *(const bf16x8*)(Whh + (size_t)2 * G * G + wb);
                ar[0][j]  = __builtin_amdgcn_mfma_f32_16x16x32_bf16(ah[0], b0, ar[0][j], 0, 0, 0);
                ar[1][j]  = __builtin_amdgcn_mfma_f32_16x16x32_bf16(ah[1], b0, ar[1][j], 0, 0, 0);
                az[0][j]  = __builtin_amdgcn_mfma_f32_16x16x32_bf16(ah[0], b1, az[0][j], 0, 0, 0);
                az[1][j]  = __builtin_amdgcn_mfma_f32_16x16x32_bf16(ah[1], b1, az[1][j], 0, 0, 0);
                anh[0][j] = __builtin_amdgcn_mfma_f32_16x16x32_bf16(ah[0], b2, anh[0][j], 0, 0, 0);
                anh[1][j] = __builtin_amdgcn_mfma_f32_16x16x32_bf16(ah[1], b2, anh[1][j], 0, 0, 0);
            }
        }
    }

    const int r4 = (lane >> 4) * 4;
    #pragma unroll
    for (int j = 0; j < 2; ++j) {
        const int col = colBase + j * 16 + l16;
        const float b0 = bih[col] + bhh[col];
        const float b1 = bih[G + col] + bhh[G + col];
        const float bi2 = bih[2 * G + col], bh2 = bhh[2 * G + col];
        #pragma unroll
        for (int i = 0; i < 2; ++i) {
            #pragma unroll
            for (int q = 0; q < 4; ++q) {
                const int row = rowBase + i * 16 + r4 + q;
                const float rr = sigmoidf_(ar[i][j][q] + b0);
                const float zz = sigmoidf_(az[i][j][q] + b1);
                const float nn = tanhf(ani[i][j][q] + bi2 + rr * (anh[i][j][q] + bh2));
                const float hp = Hprev[(size_t)row * G + col];
                const float hv = (1.f - zz) * nn + zz * hp;
                Hnew[(size_t)row * G + col] = hv;
                Hnewb[(size_t)row * G + col] = (short)f2bf(hv);
            }
        }
    }
}

__device__ __forceinline__ void gemm_tile(
    const short* __restrict__ Xb, const short* __restrict__ Wb,
    const float* __restrict__ bias, float* __restrict__ Out,
    int Ncols, int K, int rowBase, int colBase, int lane)
{
    const int l16 = lane & 15;
    const int kb8 = (lane >> 4) * 8;
    const f32x4 z4 = {0.f, 0.f, 0.f, 0.f};
    f32x4 acc[2][2] = {{z4, z4}, {z4, z4}};

    for (int kc = 0; kc < K; kc += 32) {
        const int k8 = kc + kb8;
        const bf16x8 a0 = *(const bf16x8*)(Xb + (size_t)(rowBase + l16) * K + k8);
        const bf16x8 a1 = *(const bf16x8*)(Xb + (size_t)(rowBase + 16 + l16) * K + k8);
        const bf16x8 b0 = *(const bf16x8*)(Wb + (size_t)(colBase + l16) * K + k8);
        const bf16x8 b1 = *(const bf16x8*)(Wb + (size_t)(colBase + 16 + l16) * K + k8);
        acc[0][0] = __builtin_amdgcn_mfma_f32_16x16x32_bf16(a0, b0, acc[0][0], 0, 0, 0);
        acc[0][1] = __builtin_amdgcn_mfma_f32_16x16x32_bf16(a0, b1, acc[0][1], 0, 0, 0);
        acc[1][0] = __builtin_amdgcn_mfma_f32_16x16x32_bf16(a1, b0, acc[1][0], 0, 0, 0);
        acc[1][1] = __builtin_amdgcn_mfma_f32_16x16x32_bf16(a1, b1, acc[1][1], 0, 0, 0);
    }
    const int r4 = (lane >> 4) * 4;
    #pragma unroll
    for (int j = 0; j < 2; ++j) {
        const int col = colBase + j * 16 + l16;
        if (col >= Ncols) continue;
        const float bv = bias[col];
        #pragma unroll
        for (int i = 0; i < 2; ++i)
            #pragma unroll
            for (int q = 0; q < 4; ++q) {
                const int row = rowBase + i * 16 + r4 + q;
                Out[(size_t)row * Ncols + col] = acc[i][j][q] + bv;
            }
    }
}

// ---------------------------------------------------------------------------
// phaseA: dec-GRU(t-1) FIRST (longest), then enc-GRU(t), rel-GRU(t).
// ---------------------------------------------------------------------------
__global__ __launch_bounds__(256) void phaseA(
    const short* __restrict__ ep, const short* __restrict__ er,
    const short* __restrict__ enc_wih, const float* __restrict__ enc_bih,
    const short* __restrict__ enc_whh, const float* __restrict__ enc_bhh,
    const short* __restrict__ rel_wih, const float* __restrict__ rel_bih,
    const short* __restrict__ rel_whh, const float* __restrict__ rel_bhh,
    const short* __restrict__ dec_wih, const float* __restrict__ dec_bih,
    const short* __restrict__ dec_whh, const float* __restrict__ dec_bhh,
    const float* __restrict__ hc, const short* __restrict__ hbc,
    float* __restrict__ hn, short* __restrict__ hbn,
    const float* __restrict__ hrc, const short* __restrict__ hrbc,
    float* __restrict__ hrn, short* __restrict__ hrbn,
    const float* __restrict__ hfc, const short* __restrict__ hfbc,
    float* __restrict__ hfn, short* __restrict__ hfbn,
    const short* __restrict__ reads_b,
    int decBlocks, int encBlocks)
{
    const int bid = blockIdx.x;
    const int wave = threadIdx.x >> 6;
    const int lane = threadIdx.x & 63;

    if (bid < decBlocks) {
        const int tile = bid * 4 + wave;                  // 1920: 160 row x 12 col
        gru_tile(hbc, 256, reads_b, 128, dec_wih, 384, dec_bih,
                 hfbc, dec_whh, dec_bhh, hfc, hfn, hfbn, D_,
                 (tile / 12) * 32, (tile % 12) * 32, lane);
    } else if (bid < decBlocks + encBlocks) {
        const int tile = (bid - decBlocks) * 4 + wave;    // 256: 32 row x 8 col
        gru_tile(ep, 16, reads_b, 128, enc_wih, 160, enc_bih,
                 hbc, enc_whh, enc_bhh, hc, hn, hbn, C_,
                 (tile >> 3) * 32, (tile & 7) * 32, lane);
    } else {
        const int tile = (bid - decBlocks - encBlocks) * 4 + wave;
        gru_tile(er, 16, nullptr, 0, rel_wih, 32, rel_bih,
                 hrbc, rel_whh, rel_bhh, hrc, hrn, hrbn, C_,
                 (tile >> 3) * 32, (tile & 7) * 32, lane);
    }
}

// ---------------------------------------------------------------------------
// phaseHeads: wp GEMM | rp GEMM | out(t-1) from bf16 hf.
// ---------------------------------------------------------------------------
__global__ __launch_bounds__(256) void phaseHeads(
    const short* __restrict__ hbn, const short* __restrict__ write_w_b,
    const float* __restrict__ write_b, float* __restrict__ wp,
    const short* __restrict__ hrbn, const short* __restrict__ read_w_b,
    const float* __restrict__ read_b, float* __restrict__ rp,
    const short* __restrict__ hfbn, const float* __restrict__ out_w,
    const float* __restrict__ out_b, float* __restrict__ predrel,
    int outT, int wpBlocks, int rpBlocks)
{
    const int bid = blockIdx.x;
    const int wave = threadIdx.x >> 6;
    const int lane = threadIdx.x & 63;

    if (bid < wpBlocks) {
        const int tile = bid * 4 + wave;                 // 416: 32 row-tiles x 13 col-tiles
        gemm_tile(hbn, write_w_b, write_b, wp, 385, C_,
                  (tile & 31) * 32, (tile >> 5) * 32, lane);
    } else if (bid < wpBlocks + rpBlocks) {
        const int tile = (bid - wpBlocks) * 4 + wave;    // 672: 32 row-tiles x 21 col-tiles
        gemm_tile(hrbn, read_w_b, read_b, rp, 645, C_,
                  (tile & 31) * 32, (tile >> 5) * 32, lane);
    } else {
        // out(t-1): 8-lane groups, 8 rows per wave; hf read as bf16
        const int widx = (bid - wpBlocks - rpBlocks) * 4 + wave;
        const int g = lane >> 3, li = lane & 7;
        const int row = widx * 8 + g;                    // < 5120
        const short* hrow = hfbn + (size_t)row * D_;
        float a0 = 0.f, a1 = 0.f;
        #pragma unroll
        for (int u = 0; u < 6; ++u) {
            const int k0 = u * 64 + li * 8;
            const bf16x8 v = *(const bf16x8*)(hrow + k0);
            #pragma unroll
            for (int r = 0; r < 8; ++r) {
                const float f = bf2f(v[r]);
                a0 = fmaf(f, out_w[k0 + r], a0);
                a1 = fmaf(f, out_w[D_ + k0 + r], a1);
            }
        }
        a0 += __shfl_xor(a0, 1); a0 += __shfl_xor(a0, 2); a0 += __shfl_xor(a0, 4);
        a1 += __shfl_xor(a1, 1); a1 += __shfl_xor(a1, 2); a1 += __shfl_xor(a1, 4);
        if (li == 0) {
            const int hh = row >> 10, aa = row & 1023;
            float* o = predrel + (((size_t)aa * H_ + hh) * TFUT_ + outT) * 2;
            o[0] = a0 + out_b[0];
            o[1] = a1 + out_b[1];
        }
    }
}

// ---------------------------------------------------------------------------
// NTM write (round-5 verbatim) + bf16 hi/lo split of updated slots.
// ---------------------------------------------------------------------------
__global__ __launch_bounds__(256) void write_mem_k(const float* __restrict__ wp,
                                                   float* __restrict__ mem,
                                                   short* __restrict__ memhi, short* __restrict__ memlo,
                                                   float* __restrict__ normsG)
{
    const int a = blockIdx.x;
    const int b = a >> 4, p = a & 15;
    __shared__ float kw[128], er[128], ad[128], red[256], ww[16], logit[16];
    __shared__ float buf[2048];
    __shared__ float beta_s, knorm_s;
    const int tid = threadIdx.x;
    const float* w = wp + (size_t)a * 385;
    if (tid < 128) {
        kw[tid] = tanhf(w[tid]);
        er[tid] = sigmoidf_(w[129 + tid]);
        ad[tid] = tanhf(w[257 + tid]);
    }
    if (tid == 0) beta_s = softplusf_(w[128]);
    __syncthreads();

    red[tid] = (tid < 128) ? kw[tid] * kw[tid] : 0.f;
    __syncthreads();
    for (int s = 128; s > 0; s >>= 1) { if (tid < s) red[tid] += red[tid + s]; __syncthreads(); }
    if (tid == 0) knorm_s = sqrtf(red[0]) + 1e-16f;
    __syncthreads();

    const int s = tid >> 4, j = tid & 15;
    float dot = 0.f, ss = 0.f;
    {
        const float* mrow = mem + ((size_t)(b * N_) + p * 16 + s) * M_;
        for (int k = j; k < 128; k += 16) { float v = mrow[k]; dot += kw[k] * v; ss += v * v; }
    }
    red[tid] = dot; __syncthreads();
    for (int st = 8; st > 0; st >>= 1) { if (j < st) red[tid] += red[tid + st]; __syncthreads(); }
    float dotf = red[s * 16];
    __syncthreads();
    red[tid] = ss; __syncthreads();
    for (int st = 8; st > 0; st >>= 1) { if (j < st) red[tid] += red[tid + st]; __syncthreads(); }
    float ssf = red[s * 16];
    if (j == 0) {
        float mn = sqrtf(ssf) + 1e-16f;
        logit[s] = beta_s * (dotf / (mn * knorm_s));
    }
    __syncthreads();
    if (tid == 0) {
        float mx = -1e30f;
        for (int i = 0; i < 16; ++i) mx = fmaxf(mx, logit[i]);
        float sum = 0.f;
        for (int i = 0; i < 16; ++i) { float e = __expf(logit[i] - mx); ww[i] = e; sum += e; }
        float inv = 1.f / sum;
        for (int i = 0; i < 16; ++i) ww[i] *= inv;
    }
    __syncthreads();
    for (int idx = tid; idx < 16 * 128; idx += 256) {
        int si = idx >> 7, m = idx & 127;
        size_t g = ((size_t)(b * N_) + p * 16 + si) * M_ + m;
        float wwv = ww[si];
        float v = mem[g] * (1.f - wwv * er[m]) + wwv * ad[m];
        mem[g] = v;
        const short hv = (short)f2bf(v);
        memhi[g] = hv;
        memlo[g] = (short)f2bf(v - bf2f(hv));
        buf[idx] = v;
    }
    __syncthreads();
    {
        float ssq = 0.f;
        #pragma unroll
        for (int i = 0; i < 8; ++i) { float v = buf[s * 128 + j + 16 * i]; ssq += v * v; }
        #pragma unroll
        for (int m = 1; m < 16; m <<= 1) ssq += __shfl_xor(ssq, m);
        if (j == 0) normsG[b * N_ + p * 16 + s] = sqrtf(ssq) + 1e-16f;
    }
}

// ---------------------------------------------------------------------------
// NTM read (round-8 verbatim; sims B from precomputed hi/lo bf16)
// ---------------------------------------------------------------------------
__global__ __launch_bounds__(256) void read_k2(const float* __restrict__ rp,
                                               const float* __restrict__ mem,
                                               const short* __restrict__ memhi,
                                               const short* __restrict__ memlo,
                                               const float* __restrict__ normsG,
                                               short* __restrict__ reads_b)
{
    const int b = blockIdx.x;
    const int h = blockIdx.y;
    __shared__ __align__(16) float kq[16 * 132];
    __shared__ float S[16 * 260];
    __shared__ float beta_s[16], knorm_s[16], inv_s[16];
    const int t = threadIdx.x;
    const int a = t >> 4;
    const int sub = t & 15;

    {
        const float* base = rp + ((size_t)(b * 16 + a)) * 645 + h * 129;
        const int k0 = sub * 8;
        float v[8]; float ss = 0.f;
        #pragma unroll
        for (int r = 0; r < 8; ++r) { v[r] = tanhf(base[k0 + r]); ss += v[r] * v[r]; }
        float* dst = kq + a * 132 + k0;
        *(float4*)dst = make_float4(v[0], v[1], v[2], v[3]);
        *(float4*)(dst + 4) = make_float4(v[4], v[5], v[6], v[7]);
        #pragma unroll
        for (int m = 1; m < 16; m <<= 1) ss += __shfl_xor(ss, m);
        if (sub == 0) {
            knorm_s[a] = sqrtf(ss) + 1e-16f;
            beta_s[a] = softplusf_(base[128]);
        }
    }
    __syncthreads();

    {
        const int wave = t >> 6, lane = t & 63;
        const int l16 = lane & 15, kb8 = (lane >> 4) * 8;
        const int slotBase = wave * 64;
        const f32x4 z4 = {0.f, 0.f, 0.f, 0.f};
        f32x4 acc[4] = {z4, z4, z4, z4};
        const short* mbh = memhi + (size_t)b * N_ * M_;
        const short* mbl = memlo + (size_t)b * N_ * M_;
        #pragma unroll
        for (int kc = 0; kc < 128; kc += 32) {
            const float* ap = kq + l16 * 132 + kc + kb8;
            bf16x8 ah, al;
            #pragma unroll
            for (int r = 0; r < 8; ++r) {
                const float av = ap[r];
                const short hv = (short)f2bf(av);
                ah[r] = hv; al[r] = (short)f2bf(av - bf2f(hv));
            }
            #pragma unroll
            for (int tt = 0; tt < 4; ++tt) {
                const size_t roff = (size_t)(slotBase + tt * 16 + l16) * M_ + kc + kb8;
                const bf16x8 bh = *(const bf16x8*)(mbh + roff);
                const bf16x8 bl = *(const bf16x8*)(mbl + roff);
                acc[tt] = __builtin_amdgcn_mfma_f32_16x16x32_bf16(ah, bh, acc[tt], 0, 0, 0);
                acc[tt] = __builtin_amdgcn_mfma_f32_16x16x32_bf16(ah, bl, acc[tt], 0, 0, 0);
                acc[tt] = __builtin_amdgcn_mfma_f32_16x16x32_bf16(al, bh, acc[tt], 0, 0, 0);
            }
        }
        const int r4 = (lane >> 4) * 4;
        #pragma unroll
        for (int tt = 0; tt < 4; ++tt) {
            const int slot = slotBase + tt * 16 + l16;
            const float nv = normsG[b * N_ + slot];
            #pragma unroll
            for (int q = 0; q < 4; ++q) {
                const int aq = r4 + q;
                const float lg = ((slot >> 4) == aq) ? -1e30f
                               : beta_s[aq] * acc[tt][q] / (nv * knorm_s[aq]);
                S[aq * 260 + slot] = lg;
            }
        }
    }
    __syncthreads();

    {
        float mx = -1e30f;
        #pragma unroll
        for (int i = 0; i < 16; ++i) mx = fmaxf(mx, S[a * 260 + sub + 16 * i]);
        #pragma unroll
        for (int m = 1; m < 16; m <<= 1) mx = fmaxf(mx, __shfl_xor(mx, m));
        float e[16]; float sum = 0.f;
        #pragma unroll
        for (int i = 0; i < 16; ++i) { e[i] = __expf(S[a * 260 + sub + 16 * i] - mx); sum += e[i]; }
        #pragma unroll
        for (int i = 0; i < 16; ++i) S[a * 260 + sub + 16 * i] = e[i];
        #pragma unroll
        for (int m = 1; m < 16; m <<= 1) sum += __shfl_xor(sum, m);
        if (sub == 0) inv_s[a] = 1.f / sum;
    }
    __syncthreads();

    {
        const int m0 = sub * 8;
        const float* mb = mem + (size_t)b * N_ * M_ + m0;
        float acc[8];
        #pragma unroll
        for (int r = 0; r < 8; ++r) acc[r] = 0.f;
        const float* Sa = S + a * 260;
        #pragma unroll 4
        for (int n = 0; n < N_; ++n) {
            const float w = Sa[n];
            const float4 v0 = *(const float4*)(mb + (size_t)n * M_);
            const float4 v1 = *(const float4*)(mb + (size_t)n * M_ + 4);
            acc[0] = fmaf(w, v0.x, acc[0]); acc[1] = fmaf(w, v0.y, acc[1]);
            acc[2] = fmaf(w, v0.z, acc[2]); acc[3] = fmaf(w, v0.w, acc[3]);
            acc[4] = fmaf(w, v1.x, acc[4]); acc[5] = fmaf(w, v1.y, acc[5]);
            acc[6] = fmaf(w, v1.z, acc[6]); acc[7] = fmaf(w, v1.w, acc[7]);
        }
        const float inv = inv_s[a];
        short pk[8];
        #pragma unroll
        for (int r = 0; r < 8; ++r) pk[r] = (short)f2bf(acc[r] * inv);
        *(bf16x8*)(reads_b + ((size_t)h * A_ + b * 16 + a) * M_ + m0) = *(bf16x8*)pk;
    }
}

__global__ __launch_bounds__(256) void cumsum_k(const float* __restrict__ past,
                                                const float* __restrict__ predrel,
                                                float* __restrict__ pred)
{
    const int idx = blockIdx.x * 256 + threadIdx.x;
    if (idx >= A_ * H_ * 2) return;
    const int c = idx & 1;
    const int ah = idx >> 1;
    const int a = ah / H_;
    float acc = past[((size_t)a * TPAST_ + TPAST_ - 1) * 2 + c];
    const float* pr = predrel + (size_t)ah * TFUT_ * 2 + c;
    float* pd = pred + (size_t)ah * TFUT_ * 2 + c;
    for (int t = 0; t < TFUT_; ++t) { acc += pr[t * 2]; pd[t * 2] = acc; }
}

extern "C" void kernel_launch(void* const* d_in, const int* in_sizes, int n_in,
                              void* d_out, int out_size, void* d_ws, size_t ws_size,
                              hipStream_t stream)
{
    const float* past       = (const float*)d_in[0];
    const float* past_rel   = (const float*)d_in[1];
    const float* ep_w1      = (const float*)d_in[2];
    const float* ep_b1      = (const float*)d_in[3];
    const float* ep_w2      = (const float*)d_in[4];
    const float* ep_b2      = (const float*)d_in[5];
    const float* er_w1      = (const float*)d_in[6];
    const float* er_b1      = (const float*)d_in[7];
    const float* er_w2      = (const float*)d_in[8];
    const float* er_b2      = (const float*)d_in[9];
    const float* enc_wih    = (const float*)d_in[10];
    const float* enc_whh    = (const float*)d_in[11];
    const float* enc_bih    = (const float*)d_in[12];
    const float* enc_bhh    = (const float*)d_in[13];
    const float* rel_wih    = (const float*)d_in[14];
    const float* rel_whh    = (const float*)d_in[15];
    const float* rel_bih    = (const float*)d_in[16];
    const float* rel_bhh    = (const float*)d_in[17];
    const float* dec_wih    = (const float*)d_in[18];
    const float* dec_whh    = (const float*)d_in[19];
    const float* dec_bih    = (const float*)d_in[20];
    const float* dec_bhh    = (const float*)d_in[21];
    const float* out_w      = (const float*)d_in[22];
    const float* out_b      = (const float*)d_in[23];
    const float* read_w     = (const float*)d_in[24];
    const float* read_b     = (const float*)d_in[25];
    const float* write_w    = (const float*)d_in[26];
    const float* write_b    = (const float*)d_in[27];
    const float* init_r     = (const float*)d_in[28];
    const float* h_bias     = (const float*)d_in[29];
    const float* h_rel_bias = (const float*)d_in[30];
    const float* h_fut_bias = (const float*)d_in[31];
    const float* mem_bias   = (const float*)d_in[32];

    float* pred    = (float*)d_out;
    float* predrel = pred + (size_t)A_ * H_ * TFUT_ * 2;

    float* ws = (float*)d_ws;
    size_t off = 0;
    auto alloc = [&](size_t n) { float* p = ws + off; off += n; return p; };
    float* h0     = alloc((size_t)A_ * C_);
    float* h1     = alloc((size_t)A_ * C_);
    float* hr0    = alloc((size_t)A_ * C_);
    float* hr1    = alloc((size_t)A_ * C_);
    float* hf0    = alloc((size_t)H_ * A_ * D_);
    float* hf1    = alloc((size_t)H_ * A_ * D_);
    float* mem    = alloc((size_t)B_ * N_ * M_);
    float* wp     = alloc((size_t)A_ * 385);
    float* rp     = alloc((size_t)A_ * 645);
    float* normsG = alloc((size_t)B_ * N_);

    short* sws = (short*)(ws + off);
    size_t soff = 0;
    auto salloc = [&](size_t n) { short* p = sws + soff; soff += n; return p; };
    short* emb_p_b   = salloc((size_t)TPAST_ * A_ * EMB_);
    short* emb_r_b   = salloc((size_t)TPAST_ * A_ * EMB_);
    short* hb0       = salloc((size_t)A_ * C_);
    short* hb1       = salloc((size_t)A_ * C_);
    short* hrb0      = salloc((size_t)A_ * C_);
    short* hrb1      = salloc((size_t)A_ * C_);
    short* hfb0      = salloc((size_t)H_ * A_ * D_);
    short* hfb1      = salloc((size_t)H_ * A_ * D_);
    short* reads_b   = salloc((size_t)H_ * A_ * M_);
    short* memhi     = salloc((size_t)B_ * N_ * M_);
    short* memlo     = salloc((size_t)B_ * N_ * M_);
    short* enc_wih_b = salloc((size_t)768 * 160);
    short* enc_whh_b = salloc((size_t)768 * 256);
    short* rel_wih_b = salloc((size_t)768 * 32);
    short* rel_whh_b = salloc((size_t)768 * 256);
    short* dec_wih_b = salloc((size_t)1152 * 384);
    short* dec_whh_b = salloc((size_t)1152 * 384);
    short* write_w_b = salloc((size_t)416 * 256);
    short* read_w_b  = salloc((size_t)672 * 256);
    (void)ws_size; (void)in_sizes; (void)n_in; (void)out_size;

    // prologue (3 dispatches)
    Cvt8 cp;
    cp.c[0] = {enc_wih, enc_wih_b, 768, 144, 160, 768 * 160};
    cp.c[1] = {enc_whh, enc_whh_b, 768, 256, 256, 768 * 256};
    cp.c[2] = {rel_wih, rel_wih_b, 768, 16, 32, 768 * 32};
    cp.c[3] = {rel_whh, rel_whh_b, 768, 256, 256, 768 * 256};
    cp.c[4] = {dec_wih, dec_wih_b, 1152, 384, 384, 1152 * 384};
    cp.c[5] = {dec_whh, dec_whh_b, 1152, 384, 384, 1152 * 384};
    cp.c[6] = {write_w, write_w_b, 385, 256, 256, 416 * 256};
    cp.c[7] = {read_w, read_w_b, 645, 256, 256, 672 * 256};
    convert_all<<<1024, 256, 0, stream>>>(cp);

    init_k<<<(B_ * N_ * M_ + 255) / 256, 256, 0, stream>>>(
        h0, h_bias, hb0, hr0, h_rel_bias, hrb0, hf0, h_fut_bias, hfb0,
        reads_b, init_r, mem, memhi, memlo, normsG, mem_bias);
    embed2_k<<<(2 * A_ * TPAST_ + 255) / 256, 256, 0, stream>>>(
        past, past_rel, ep_w1, ep_b1, ep_w2, ep_b2, er_w1, er_b1, er_w2, er_b2,
        emb_p_b, emb_r_b);

    float *hc = h0, *hn = h1, *hrc = hr0, *hrn = hr1, *hfc = hf0, *hfn = hf1;
    short *hbc = hb0, *hbn = hb1, *hrbc = hrb0, *hrbn = hrb1, *hfbc = hfb0, *hfbn = hfb1;

    const dim3 g_read(B_, H_);   // (64, 5)

    for (int t = 0; t < TTOT_; ++t) {
        const short* ep = (t < TPAST_) ? emb_p_b + (size_t)t * A_ * EMB_ : nullptr;
        const short* er = (t < TPAST_) ? emb_r_b + (size_t)t * A_ * EMB_ : nullptr;

        // phase A: dec(t-1) [t>=1] + enc(t) + rel(t)
        const int decBlocks = (t == 0) ? 0 : 480;
        phaseA<<<decBlocks + 128, 256, 0, stream>>>(
            ep, er,
            enc_wih_b, enc_bih, enc_whh_b, enc_bhh,
            rel_wih_b, rel_bih, rel_whh_b, rel_bhh,
            dec_wih_b, dec_bih, dec_whh_b, dec_bhh,
            hc, hbc, hn, hbn,
            hrc, hrbc, hrn, hrbn,
            hfc, hfbc, hfn, hfbn,
            reads_b, decBlocks, 64);

        // phase Heads: wp GEMM + rp GEMM (+ out(t-1) when t>=21)
        const int gridH = (t >= 21) ? 432 : 272;
        phaseHeads<<<gridH, 256, 0, stream>>>(
            hbn, write_w_b, write_b, wp,
            hrbn, read_w_b, read_b, rp,
            hfbn, out_w, out_b, predrel, t - 21, 104, 168);

        // memory write
        write_mem_k<<<A_, 256, 0, stream>>>(wp, mem, memhi, memlo, normsG);

        // memory read -> reads_b(t)
        read_k2<<<g_read, 256, 0, stream>>>(rp, mem, memhi, memlo, normsG, reads_b);

        // swaps
        float* tf; short* ts;
        tf = hc; hc = hn; hn = tf;       ts = hbc; hbc = hbn; hbn = ts;
        tf = hrc; hrc = hrn; hrn = tf;   ts = hrbc; hrbc = hrbn; hrbn = ts;
        if (t >= 1) {
            tf = hfc; hfc = hfn; hfn = tf;  ts = hfbc; hfbc = hfbn; hfbn = ts;
        }
    }

    // epilogue: dec(49), out(49), cumsum
    phaseA<<<480, 256, 0, stream>>>(
        nullptr, nullptr,
        enc_wih_b, enc_bih, enc_whh_b, enc_bhh,
        rel_wih_b, rel_bih, rel_whh_b, rel_bhh,
        dec_wih_b, dec_bih, dec_whh_b, dec_bhh,
        hc, hbc, hn, hbn,
        hrc, hrbc, hrn, hrbn,
        hfc, hfbc, hfn, hfbn,
        reads_b, 480, 0);
    phaseHeads<<<160, 256, 0, stream>>>(
        hbn, write_w_b, write_b, wp,
        hrbn, read_w_b, read_b, rp,
        hfbn, out_w, out_b, predrel, TFUT_ - 1, 0, 0);
    cumsum_k<<<(A_ * H_ * 2 + 255) / 256, 256, 0, stream>>>(past, predrel, pred);
}